// Round 14
// baseline (1888.395 us; speedup 1.0000x reference)
//
#include <hip/hip_runtime.h>
#include <math.h>

#define TID ((int)threadIdx.x)

// problem sizes
constexpr int Bsz = 1000, DIN = 1024, Dm = 512, C1 = 1204, C0 = 1203, Ltok = 77;
constexpr int NINS = 4, NEX = 5, KSEL = 32, KTOP = 5, NHEAD = 8, DH = 64, MLPD = 2048, NL = 4, Pn = 160;
constexpr float TEMPc = 50.0f;

typedef __attribute__((ext_vector_type(8))) short short8;
typedef __attribute__((ext_vector_type(4))) float f32x4;
typedef __attribute__((address_space(1))) const void g1void;
typedef __attribute__((address_space(3))) void l3void;
#define GLOAD16(g, l) __builtin_amdgcn_global_load_lds((g1void*)(g), (l3void*)(l), 16, 0, 0)

__device__ __forceinline__ float sigf(float z) {  // accurate (rerank path)
  return z >= 0.f ? 1.f / (1.f + expf(-z)) : expf(z) / (1.f + expf(z));
}

__device__ __forceinline__ float qgelu(float v) {  // fast quickgelu (bgemm epilogue)
  return v * __fdividef(1.f, 1.f + __expf(-1.702f * v));
}

__device__ __forceinline__ unsigned short f2bfu(float f) {  // round-to-nearest-even
  unsigned u = __builtin_bit_cast(unsigned, f);
  u += 0x7fffu + ((u >> 16) & 1u);
  return (unsigned short)(u >> 16);
}
__device__ __forceinline__ short f2bf(float f) { return (short)f2bfu(f); }

__device__ __forceinline__ void epi_store(f32x4 v, const float* bias, int colb, size_t off,
                                          int mode, float* Cf, short* Cb, float* Xres) {
  if (bias) {
    float4 bv = *(const float4*)(bias + colb);
    v[0] += bv.x; v[1] += bv.y; v[2] += bv.z; v[3] += bv.w;
  }
  if (mode == 0) {
    *(float4*)(Cf + off) = make_float4(v[0], v[1], v[2], v[3]);
  } else if (mode == 1) {
    float4* p = (float4*)(Xres + off);
    float4 o = *p;
    o.x += v[0]; o.y += v[1]; o.z += v[2]; o.w += v[3];
    *p = o;
  } else {
    if (mode == 2) {
      v[0] = qgelu(v[0]); v[1] = qgelu(v[1]); v[2] = qgelu(v[2]); v[3] = qgelu(v[3]);
    }
    uint2 pk;
    pk.x = (unsigned)f2bfu(v[0]) | ((unsigned)f2bfu(v[1]) << 16);
    pk.y = (unsigned)f2bfu(v[2]) | ((unsigned)f2bfu(v[3]) << 16);
    *(uint2*)(Cb + off) = pk;
  }
}

// ================= bf16 MFMA GEMM (128x128, BK=64): C = A @ Wt^T + bias =================
// R9 config (best measured): single 32KB LDS buffer, 4 blocks/CU, BK=64.
__global__ __launch_bounds__(256, 4) void bgemm_k(const short* __restrict__ A,
                                                  const short* __restrict__ Bt,
                                                  const float* __restrict__ bias,
                                                  float* __restrict__ Cf,
                                                  short* __restrict__ Cb,
                                                  float* __restrict__ Xres,
                                                  int M, int N, int K, int mode) {
  __shared__ short As[8192];  // 128 rows x 64 k (two 32-k subtiles)
  __shared__ short Bs[8192];
  int nwg = gridDim.x * gridDim.y;
  int orig = blockIdx.y * gridDim.x + blockIdx.x;
  int xcd = orig & 7, lid = orig >> 3;
  int q = nwg >> 3, r = nwg & 7;
  int swz = (xcd < r ? xcd * (q + 1) : r * (q + 1) + (xcd - r) * q) + lid;
  int row0 = (swz / gridDim.x) * 128, col0 = (swz % gridDim.x) * 128;
  int lane = TID & 63;
  int w = TID >> 6;
  int wr = (TID >> 7) & 1, wc = (TID >> 6) & 1;
  int skb = (TID >> 4) & 3, si = TID & 15;
  f32x4 acc[4][4] = {};
  int nt = K >> 6;
  int kb = lane >> 4, i = lane & 15;
  for (int t = 0; t < nt; ++t) {
#pragma unroll
    for (int s = 0; s < 2; ++s) {
#pragma unroll
      for (int c = 0; c < 2; ++c) {
        int row = (c * 4 + w) * 16 + si;
        int k0 = (t << 6) + (s << 5) + skb * 8;
        GLOAD16(A + (size_t)(row0 + row) * K + k0, As + s * 4096 + (c * 256 + w * 64) * 8);
        GLOAD16(Bt + (size_t)(col0 + row) * K + k0, Bs + s * 4096 + (c * 256 + w * 64) * 8);
      }
    }
    __syncthreads();
#pragma unroll
    for (int s = 0; s < 2; ++s) {
      const short* Ab = As + s * 4096;
      const short* Bb = Bs + s * 4096;
      short8 af[4], bfr[4];
#pragma unroll
      for (int m = 0; m < 4; ++m)
        af[m] = *(const short8*)(Ab + ((((wr * 4 + m) * 4 + kb) * 16 + i) * 8));
#pragma unroll
      for (int n = 0; n < 4; ++n)
        bfr[n] = *(const short8*)(Bb + ((((wc * 4 + n) * 4 + kb) * 16 + i) * 8));
#pragma unroll
      for (int m = 0; m < 4; ++m)
#pragma unroll
        for (int n = 0; n < 4; ++n)
          acc[m][n] = __builtin_amdgcn_mfma_f32_16x16x32_bf16(bfr[n], af[m], acc[m][n], 0, 0, 0);
    }
    __syncthreads();
  }
  int li = lane & 15, lg = lane >> 4;
#pragma unroll
  for (int m = 0; m < 4; ++m) {
    int row = row0 + wr * 64 + m * 16 + li;
    if (row >= M) continue;
#pragma unroll
    for (int n = 0; n < 4; ++n) {
      int colb = col0 + wc * 64 + n * 16 + lg * 4;
      epi_store(acc[m][n], bias, colb, (size_t)row * N + colb, mode, Cf, Cb, Xres);
    }
  }
}

// ===== bf16 MFMA GEMM (128x128, BK=128): for occupancy-starved grids (N=512, big M) =====
// 64KB LDS is NOT binding when grid < 2 blocks/CU anyway -> halves block-steps for free.
__global__ __launch_bounds__(256, 4) void bgemm_k128(const short* __restrict__ A,
                                                     const short* __restrict__ Bt,
                                                     const float* __restrict__ bias,
                                                     float* __restrict__ Cf,
                                                     short* __restrict__ Cb,
                                                     float* __restrict__ Xres,
                                                     int M, int N, int K, int mode) {
  __shared__ short As[16384];  // 4 subtiles x 128 rows x 32 k
  __shared__ short Bs[16384];
  int nwg = gridDim.x * gridDim.y;
  int orig = blockIdx.y * gridDim.x + blockIdx.x;
  int xcd = orig & 7, lid = orig >> 3;
  int q = nwg >> 3, r = nwg & 7;
  int swz = (xcd < r ? xcd * (q + 1) : r * (q + 1) + (xcd - r) * q) + lid;
  int row0 = (swz / gridDim.x) * 128, col0 = (swz % gridDim.x) * 128;
  int lane = TID & 63;
  int w = TID >> 6;
  int wr = (TID >> 7) & 1, wc = (TID >> 6) & 1;
  int skb = (TID >> 4) & 3, si = TID & 15;
  f32x4 acc[4][4] = {};
  int nt = K >> 7;  // K % 128 == 0 (512, 2048)
  int kb = lane >> 4, i = lane & 15;
  for (int t = 0; t < nt; ++t) {
#pragma unroll
    for (int s = 0; s < 4; ++s) {
#pragma unroll
      for (int c = 0; c < 2; ++c) {
        int row = (c * 4 + w) * 16 + si;
        int k0 = (t << 7) + (s << 5) + skb * 8;
        GLOAD16(A + (size_t)(row0 + row) * K + k0, As + s * 4096 + (c * 256 + w * 64) * 8);
        GLOAD16(Bt + (size_t)(col0 + row) * K + k0, Bs + s * 4096 + (c * 256 + w * 64) * 8);
      }
    }
    __syncthreads();
#pragma unroll
    for (int s = 0; s < 4; ++s) {
      const short* Ab = As + s * 4096;
      const short* Bb = Bs + s * 4096;
      short8 af[4], bfr[4];
#pragma unroll
      for (int m = 0; m < 4; ++m)
        af[m] = *(const short8*)(Ab + ((((wr * 4 + m) * 4 + kb) * 16 + i) * 8));
#pragma unroll
      for (int n = 0; n < 4; ++n)
        bfr[n] = *(const short8*)(Bb + ((((wc * 4 + n) * 4 + kb) * 16 + i) * 8));
#pragma unroll
      for (int m = 0; m < 4; ++m)
#pragma unroll
        for (int n = 0; n < 4; ++n)
          acc[m][n] = __builtin_amdgcn_mfma_f32_16x16x32_bf16(bfr[n], af[m], acc[m][n], 0, 0, 0);
    }
    __syncthreads();
  }
  int li = lane & 15, lg = lane >> 4;
#pragma unroll
  for (int m = 0; m < 4; ++m) {
    int row = row0 + wr * 64 + m * 16 + li;
    if (row >= M) continue;
#pragma unroll
    for (int n = 0; n < 4; ++n) {
      int colb = col0 + wc * 64 + n * 16 + lg * 4;
      epi_store(acc[m][n], bias, colb, (size_t)row * N + colb, mode, Cf, Cb, Xres);
    }
  }
}

// ========== tall bf16 MFMA GEMM (256x128, 512 thr, BK=64) — r12 routing kept ==========
__global__ __launch_bounds__(512, 4) void bgemm_tall_k(const short* __restrict__ A,
                                                       const short* __restrict__ Bt,
                                                       const float* __restrict__ bias,
                                                       float* __restrict__ Cf,
                                                       short* __restrict__ Cb,
                                                       float* __restrict__ Xres,
                                                       int M, int N, int K, int mode) {
  __shared__ short As[16384];
  __shared__ short Bs[8192];
  int nwg = gridDim.x * gridDim.y;
  int orig = blockIdx.y * gridDim.x + blockIdx.x;
  int xcd = orig & 7, lid = orig >> 3;
  int q = nwg >> 3, r = nwg & 7;
  int swz = (xcd < r ? xcd * (q + 1) : r * (q + 1) + (xcd - r) * q) + lid;
  int row0 = (swz / gridDim.x) * 256, col0 = (swz % gridDim.x) * 128;
  int lane = TID & 63;
  int w = TID >> 6;
  int wr = w >> 1, wc = w & 1;
  f32x4 acc[4][4] = {};
  int nt = K >> 6;
  int kb = lane >> 4, i = lane & 15;
  int sg0 = TID >> 6, skb = (TID >> 4) & 3, si = TID & 15;
  for (int t = 0; t < nt; ++t) {
#pragma unroll
    for (int s = 0; s < 2; ++s) {
      int k0 = (t << 6) + (s << 5) + skb * 8;
#pragma unroll
      for (int c0 = 0; c0 < 2; ++c0) {
        int row = (c0 * 8 + sg0) * 16 + si;
        GLOAD16(A + (size_t)(row0 + row) * K + k0, As + s * 8192 + (c0 * 512 + TID) * 8);
      }
      {
        int row = sg0 * 16 + si;
        GLOAD16(Bt + (size_t)(col0 + row) * K + k0, Bs + s * 4096 + TID * 8);
      }
    }
    __syncthreads();
#pragma unroll
    for (int s = 0; s < 2; ++s) {
      const short* Ab = As + s * 8192;
      const short* Bb = Bs + s * 4096;
      short8 af[4], bfr[4];
#pragma unroll
      for (int m = 0; m < 4; ++m)
        af[m] = *(const short8*)(Ab + ((((wr * 4 + m) * 4 + kb) * 16 + i) * 8));
#pragma unroll
      for (int n = 0; n < 4; ++n)
        bfr[n] = *(const short8*)(Bb + ((((wc * 4 + n) * 4 + kb) * 16 + i) * 8));
#pragma unroll
      for (int m = 0; m < 4; ++m)
#pragma unroll
        for (int n = 0; n < 4; ++n)
          acc[m][n] = __builtin_amdgcn_mfma_f32_16x16x32_bf16(bfr[n], af[m], acc[m][n], 0, 0, 0);
    }
    __syncthreads();
  }
  int li = lane & 15, lg = lane >> 4;
#pragma unroll
  for (int m = 0; m < 4; ++m) {
    int row = row0 + wr * 64 + m * 16 + li;
    if (row >= M) continue;
#pragma unroll
    for (int n = 0; n < 4; ++n) {
      int colb = col0 + wc * 64 + n * 16 + lg * 4;
      epi_store(acc[m][n], bias, colb, (size_t)row * N + colb, mode, Cf, Cb, Xres);
    }
  }
}

// ======== split-K bf16 MFMA GEMM: P[z][M][N] partials (agg starved GEMMs) ========
__global__ __launch_bounds__(256, 4) void bgemm_sk_k(const short* __restrict__ A,
                                                     const short* __restrict__ Bt,
                                                     float* __restrict__ P,
                                                     int M, int N, int K, int KC) {
  __shared__ short As[8192];
  __shared__ short Bs[8192];
  int nwg = gridDim.x * gridDim.y;
  int orig = blockIdx.y * gridDim.x + blockIdx.x;
  int xcd = orig & 7, lid = orig >> 3;
  int q = nwg >> 3, r = nwg & 7;
  int swz = (xcd < r ? xcd * (q + 1) : r * (q + 1) + (xcd - r) * q) + lid;
  int row0 = (swz / gridDim.x) * 128, col0 = (swz % gridDim.x) * 128;
  int kbeg = blockIdx.z * KC;
  int lane = TID & 63;
  int w = TID >> 6;
  int wr = (TID >> 7) & 1, wc = (TID >> 6) & 1;
  int skb = (TID >> 4) & 3, si = TID & 15;
  f32x4 acc[4][4] = {};
  int nt = KC >> 6;
  int kb = lane >> 4, i = lane & 15;
  for (int t = 0; t < nt; ++t) {
#pragma unroll
    for (int s = 0; s < 2; ++s) {
#pragma unroll
      for (int c = 0; c < 2; ++c) {
        int row = (c * 4 + w) * 16 + si;
        int k0 = kbeg + (t << 6) + (s << 5) + skb * 8;
        GLOAD16(A + (size_t)(row0 + row) * K + k0, As + s * 4096 + (c * 256 + w * 64) * 8);
        GLOAD16(Bt + (size_t)(col0 + row) * K + k0, Bs + s * 4096 + (c * 256 + w * 64) * 8);
      }
    }
    __syncthreads();
#pragma unroll
    for (int s = 0; s < 2; ++s) {
      const short* Ab = As + s * 4096;
      const short* Bb = Bs + s * 4096;
      short8 af[4], bfr[4];
#pragma unroll
      for (int m = 0; m < 4; ++m)
        af[m] = *(const short8*)(Ab + ((((wr * 4 + m) * 4 + kb) * 16 + i) * 8));
#pragma unroll
      for (int n = 0; n < 4; ++n)
        bfr[n] = *(const short8*)(Bb + ((((wc * 4 + n) * 4 + kb) * 16 + i) * 8));
#pragma unroll
      for (int m = 0; m < 4; ++m)
#pragma unroll
        for (int n = 0; n < 4; ++n)
          acc[m][n] = __builtin_amdgcn_mfma_f32_16x16x32_bf16(bfr[n], af[m], acc[m][n], 0, 0, 0);
    }
    __syncthreads();
  }
  float* Pz = P + (size_t)blockIdx.z * M * N;
  int li = lane & 15, lg = lane >> 4;
#pragma unroll
  for (int m = 0; m < 4; ++m) {
    int row = row0 + wr * 64 + m * 16 + li;
    if (row >= M) continue;
#pragma unroll
    for (int n = 0; n < 4; ++n) {
      int colb = col0 + wc * 64 + n * 16 + lg * 4;
      *(float4*)(Pz + (size_t)row * N + colb) = make_float4(acc[m][n][0], acc[m][n][1], acc[m][n][2], acc[m][n][3]);
    }
  }
}

// reduce split-K partials into residual: Xres[i] += sum_s P[s][i] + bias[i % N]
__global__ __launch_bounds__(256) void reduce_res_k(const float* __restrict__ P,
                                                    const float* __restrict__ bias,
                                                    float* __restrict__ Xres,
                                                    int MN, int N, int S) {
  int i = blockIdx.x * 256 + TID;
  if (i >= MN) return;
  float v = bias[i % N];
  for (int s = 0; s < S; ++s) v += P[(size_t)s * MN + i];
  Xres[i] += v;
}

// ============ weight convert+transpose: W[NL][K][N] f32 -> Wt[NL][N][K] bf16 ============
__global__ __launch_bounds__(256) void wconv_k(const float* __restrict__ W,
                                               short* __restrict__ Wt, int K, int N) {
  int l = blockIdx.z;
  const float* Wl = W + (size_t)l * K * N;
  short* Wtl = Wt + (size_t)l * K * N;
  __shared__ float t[32][33];
  int n0 = blockIdx.x * 32, k0 = blockIdx.y * 32;
  int tx = TID & 31, ty = TID >> 5;
#pragma unroll
  for (int u = 0; u < 4; ++u)
    t[ty + u * 8][tx] = Wl[(size_t)(k0 + ty + u * 8) * N + n0 + tx];
  __syncthreads();
#pragma unroll
  for (int u = 0; u < 4; ++u)
    Wtl[(size_t)(n0 + ty + u * 8) * K + k0 + tx] = f2bf(t[tx][ty + u * 8]);
}

// ---------------- fp32 split-K GEMM (classifier path, exact) ----------------
__global__ __launch_bounds__(256) void gemm32s_k(const float* __restrict__ A,
                                                 const float* __restrict__ W,
                                                 float* __restrict__ P,
                                                 int M, int N, int K, int KC) {
  __shared__ float As[64][17];
  __shared__ float Ws[16][65];
  int tx = TID & 15, ty = TID >> 4;
  int row0 = blockIdx.y * 64, col0 = blockIdx.x * 64;
  int kbeg = blockIdx.z * KC;
  int kend = kbeg + KC < K ? kbeg + KC : K;
  float acc[4][4] = {};
  for (int k0 = kbeg; k0 < kend; k0 += 16) {
    {
      int r = TID >> 2, c4 = (TID & 3) * 4;
      int gr = row0 + r;
#pragma unroll
      for (int u = 0; u < 4; ++u) {
        int gc = k0 + c4 + u;
        As[r][c4 + u] = (gr < M && gc < K) ? A[gr * K + gc] : 0.f;
      }
    }
    {
      int c = TID & 63;
      int gc = col0 + c;
#pragma unroll
      for (int u = 0; u < 4; ++u) {
        int rr = (TID >> 6) * 4 + u;
        int gk = k0 + rr;
        Ws[rr][c] = (gk < K && gc < N) ? W[gk * N + gc] : 0.f;
      }
    }
    __syncthreads();
#pragma unroll
    for (int kk = 0; kk < 16; ++kk) {
      float a[4], b[4];
#pragma unroll
      for (int i = 0; i < 4; ++i) a[i] = As[ty * 4 + i][kk];
#pragma unroll
      for (int j = 0; j < 4; ++j) b[j] = Ws[kk][tx * 4 + j];
#pragma unroll
      for (int i = 0; i < 4; ++i)
#pragma unroll
        for (int j = 0; j < 4; ++j) acc[i][j] += a[i] * b[j];
    }
    __syncthreads();
  }
  float* Ps = P + (size_t)blockIdx.z * M * N;
#pragma unroll
  for (int i = 0; i < 4; ++i) {
    int rrow = row0 + ty * 4 + i;
    if (rrow >= M) continue;
#pragma unroll
    for (int j = 0; j < 4; ++j) {
      int ccol = col0 + tx * 4 + j;
      if (ccol >= N) continue;
      Ps[(size_t)rrow * N + ccol] = acc[i][j];
    }
  }
}

__global__ __launch_bounds__(256) void reduce_k(const float* __restrict__ P,
                                                const float* __restrict__ bias,
                                                float* __restrict__ C,
                                                float* __restrict__ C2,
                                                int MN, int N, int S) {
  int i = blockIdx.x * 256 + TID;
  if (i >= MN) return;
  float v = 0.f;
  for (int s = 0; s < S; ++s) v += P[(size_t)s * MN + i];
  if (bias) v += bias[i % N];
  C[i] = v;
  if (C2) C2[i] = v;
}

// ---------------- row normalize: h = TEMP * h / ||h|| ----------------
__global__ __launch_bounds__(256) void rownorm_k(float* __restrict__ h) {
  int r = blockIdx.x;
  float* x = h + r * Dm;
  float v0 = x[TID], v1 = x[TID + 256];
  __shared__ float s1[256];
  s1[TID] = v0 * v0 + v1 * v1;
  __syncthreads();
  for (int s = 128; s; s >>= 1) { if (TID < s) s1[TID] += s1[TID + s]; __syncthreads(); }
  float sc = TEMPc / sqrtf(s1[0]);
  x[TID] = v0 * sc;
  x[TID + 256] = v1 * sc;
}

// ---------------- entropy (double accumulation, exact) ----------------
__global__ __launch_bounds__(256) void entropy_k(const float* __restrict__ logits,
                                                 double* __restrict__ ent) {
  int r = blockIdx.x;
  double acc = 0.0;
  for (int c = TID; c < C1; c += 256) {
    float z = logits[r * C1 + c];
    float ls = z >= 0.f ? -log1pf(expf(-z)) : z - log1pf(expf(z));
    float p = z >= 0.f ? 1.f / (1.f + expf(-z)) : expf(z) / (1.f + expf(z));
    acc += (double)(-p * ls);
  }
  __shared__ double sd[256];
  sd[TID] = acc;
  __syncthreads();
  for (int s = 128; s; s >>= 1) { if (TID < s) sd[TID] += sd[TID + s]; __syncthreads(); }
  if (TID == 0) ent[r] = sd[0];
}

// ---------------- top-32 over entropy[1000] (desc, ties -> lower idx) ----------------
__global__ __launch_bounds__(256) void top32_k(const double* __restrict__ ent,
                                               int* __restrict__ selidx,
                                               float* __restrict__ out2) {
  __shared__ double v[1000];
  __shared__ double wv[4];
  __shared__ int wi[4];
  for (int i = TID; i < 1000; i += 256) v[i] = ent[i];
  __syncthreads();
  int w = TID >> 6, lane = TID & 63;
  for (int r = 0; r < KSEL; ++r) {
    double bv = -1e300; int bi = 1 << 30;
    for (int i = TID; i < 1000; i += 256) {
      double x = v[i];
      if (x > bv || (x == bv && i < bi)) { bv = x; bi = i; }
    }
#pragma unroll
    for (int off = 32; off; off >>= 1) {
      double ov = __shfl_xor(bv, off, 64);
      int oi = __shfl_xor(bi, off, 64);
      if (ov > bv || (ov == bv && oi < bi)) { bv = ov; bi = oi; }
    }
    if (lane == 0) { wv[w] = bv; wi[w] = bi; }
    __syncthreads();
    if (TID == 0) {
      double fv = wv[0]; int fi = wi[0];
#pragma unroll
      for (int u = 1; u < 4; ++u)
        if (wv[u] > fv || (wv[u] == fv && wi[u] < fi)) { fv = wv[u]; fi = wi[u]; }
      selidx[r] = fi; out2[r] = (float)fi; v[fi] = -1e300;
    }
    __syncthreads();
  }
}

// ---------------- per-selected-row top-5 over first 1203 logits ----------------
__global__ __launch_bounds__(256) void top5_k(const float* __restrict__ logits,
                                              const int* __restrict__ selidx,
                                              int* __restrict__ topk) {
  int s = blockIdx.x;
  int row = selidx[s];
  __shared__ float v[C0];
  __shared__ float wv[4];
  __shared__ int wi[4];
  for (int i = TID; i < C0; i += 256) v[i] = logits[row * C1 + i];
  __syncthreads();
  int w = TID >> 6, lane = TID & 63;
  for (int r = 0; r < KTOP; ++r) {
    float bv = -INFINITY; int bi = 1 << 30;
    for (int i = TID; i < C0; i += 256) {
      float x = v[i];
      if (x > bv || (x == bv && i < bi)) { bv = x; bi = i; }
    }
#pragma unroll
    for (int off = 32; off; off >>= 1) {
      float ov = __shfl_xor(bv, off, 64);
      int oi = __shfl_xor(bi, off, 64);
      if (ov > bv || (ov == bv && oi < bi)) { bv = ov; bi = oi; }
    }
    if (lane == 0) { wv[w] = bv; wi[w] = bi; }
    __syncthreads();
    if (TID == 0) {
      float fv = wv[0]; int fi = wi[0];
#pragma unroll
      for (int u = 1; u < 4; ++u)
        if (wv[u] > fv || (wv[u] == fv && wi[u] < fi)) { fv = wv[u]; fi = wi[u]; }
      topk[s * KTOP + r] = fi; v[fi] = -INFINITY;
    }
    __syncthreads();
  }
}

__global__ void eos_k(const int* __restrict__ eos_index, const int* __restrict__ topk,
                      int* __restrict__ eosl) {
  for (int p = TID; p < Pn; p += 256) eosl[p] = eos_index[topk[p]] + 2 * NINS;
}

__global__ void gather_h_k(const float* __restrict__ h, const int* __restrict__ selidx,
                           float* __restrict__ hsel) {
  int s = blockIdx.x;
  int row = selidx[s];
  for (int d = TID; d < Dm; d += 256) hsel[s * Dm + d] = h[row * Dm + d];
}

// ---------------- build aggregator input [160,9,512] f32 ----------------
__global__ __launch_bounds__(256) void build_agg_k(const float* __restrict__ ins,
                                                   const float* __restrict__ sampled,
                                                   const float* __restrict__ ex,
                                                   const int* __restrict__ topk,
                                                   float* __restrict__ X) {
  int b = blockIdx.x;
  int p = b / 9, tok = b % 9;
  int s = p / KTOP;
#pragma unroll
  for (int u = 0; u < 2; ++u) {
    int d = TID + u * 256;
    float v;
    if (tok < NINS) v = ins[tok * Dm + d] + sampled[s * Dm + d] * (1.f / TEMPc);
    else {
      int cls = topk[p];
      v = ex[(cls * NEX + (tok - NINS)) * Dm + d];
    }
    X[b * Dm + d] = v;
  }
}

__global__ void save_ins_k(const float* __restrict__ X, float* __restrict__ insbuf) {
  int p = blockIdx.x;
  for (int i = TID; i < NINS * Dm; i += 256) insbuf[p * NINS * Dm + i] = X[p * 9 * Dm + i];
}

// ---------------- build txt input chunk (f32) ----------------
__global__ __launch_bounds__(256) void build_txt_k(const float* __restrict__ token_seq,
                                                   const float* __restrict__ insbuf,
                                                   const float* __restrict__ pos,
                                                   const int* __restrict__ topk,
                                                   float* __restrict__ X, int p0) {
  int b = blockIdx.x;
  int pl = b / Ltok, tok = b % Ltok;
  int p = p0 + pl;
  int cls = topk[p];
#pragma unroll
  for (int u = 0; u < 2; ++u) {
    int d = TID + u * 256;
    float v;
    if (tok < 2) v = token_seq[(cls * Ltok + tok) * Dm + d];
    else if (tok < 2 + NINS) v = insbuf[(p * NINS + (tok - 2)) * Dm + d];
    else v = token_seq[(cls * Ltok + (tok - NINS)) * Dm + d];
    X[b * Dm + d] = v + pos[tok * Dm + d];
  }
}

// ------- layernorm: f32 in -> bf16 out. 2 rows/block, float4 loads, packed stores -------
__global__ __launch_bounds__(256) void ln_k(const float* __restrict__ X,
                                            const float* __restrict__ g,
                                            const float* __restrict__ b,
                                            short* __restrict__ A) {
  int t = blockIdx.x * 2 + (TID >> 7);  // row
  int l = TID & 127;                    // 128 threads per row, 4 elems each
  const float* x = X + (size_t)t * Dm;
  float4 v = ((const float4*)x)[l];
  float s1 = v.x + v.y + v.z + v.w;
  float s2 = v.x * v.x + v.y * v.y + v.z * v.z + v.w * v.w;
#pragma unroll
  for (int off = 32; off; off >>= 1) {
    s1 += __shfl_xor(s1, off, 64);
    s2 += __shfl_xor(s2, off, 64);
  }
  __shared__ float w1[4], w2[4];
  int w = TID >> 6;
  if ((TID & 63) == 0) { w1[w] = s1; w2[w] = s2; }
  __syncthreads();
  int wb = (TID >> 7) << 1;
  float S1 = w1[wb] + w1[wb + 1];
  float S2 = w2[wb] + w2[wb + 1];
  float mean = S1 * (1.f / 512.f);
  float var = S2 * (1.f / 512.f) - mean * mean;
  float inv = rsqrtf(var + 1e-5f);
  float4 gv = ((const float4*)g)[l];
  float4 bv = ((const float4*)b)[l];
  uint2 pk;
  pk.x = (unsigned)f2bfu((v.x - mean) * inv * gv.x + bv.x) |
         ((unsigned)f2bfu((v.y - mean) * inv * gv.y + bv.y) << 16);
  pk.y = (unsigned)f2bfu((v.z - mean) * inv * gv.z + bv.z) |
         ((unsigned)f2bfu((v.w - mean) * inv * gv.w + bv.w) << 16);
  *(uint2*)(A + (size_t)t * Dm + l * 4) = pk;
}

// ======== txt attention, MFMA bf16: one block per (seq, head), 5 waves ========
__global__ __launch_bounds__(320) void attn_tx_k(const short* __restrict__ qkv,
                                                 short* __restrict__ O, int S) {
  __shared__ short Kf[5120];
  __shared__ short Vt[6144];
  __shared__ short Pf[5][1536];
  int p = blockIdx.x >> 3, h = blockIdx.x & 7;
  int base = p * S;
  for (int c = TID; c < 640; c += 320) {
    int i = c & 15, kb = (c >> 4) & 7, g = c >> 7;
    int j = g * 16 + i;
    short8 v = {};
    if (j < S) v = *(const short8*)(qkv + (size_t)(base + j) * 1536 + 512 + h * 64 + kb * 8);
    *(short8*)(Kf + c * 8) = v;
  }
  for (int c = TID; c < 640; c += 320) {
    int j = c >> 3;
    int d0 = (c & 7) * 8;
    short8 v = {};
    if (j < S) v = *(const short8*)(qkv + (size_t)(base + j) * 1536 + 1024 + h * 64 + d0);
    int kb = j >> 3, jj = j & 7;
#pragma unroll
    for (int u = 0; u < 8; ++u) {
      int d = d0 + u;
      Vt[(((d >> 4) * 12 + kb) * 16 + (d & 15)) * 8 + jj] = v[u];
    }
  }
  for (int c = TID; c < 128; c += 320) {
    int i = c & 15, kb = 10 + ((c >> 4) & 1), g = c >> 5;
    *(short8*)(Vt + ((g * 12 + kb) * 16 + i) * 8) = short8{};
  }
  __syncthreads();
  int w = TID >> 6, lane = TID & 63;
  int li = lane & 15, lg = lane >> 4;
  short8 aq[2];
#pragma unroll
  for (int ks = 0; ks < 2; ++ks)
    aq[ks] = *(const short8*)(qkv + (size_t)(base + w * 16 + li) * 1536 + h * 64 + ks * 32 + lg * 8);
  f32x4 accs[5] = {};
#pragma unroll
  for (int t = 0; t < 5; ++t)
#pragma unroll
    for (int ks = 0; ks < 2; ++ks) {
      short8 bk = *(const short8*)(Kf + ((t * 8 + ks * 4 + lg) * 16 + li) * 8);
      accs[t] = __builtin_amdgcn_mfma_f32_16x16x32_bf16(aq[ks], bk, accs[t], 0, 0, 0);
    }
  int rowg = w * 16 + lg * 4;
#pragma unroll
  for (int r = 0; r < 4; ++r) {
    int row = rowg + r;
    float v[5];
    float mx = -1e30f;
#pragma unroll
    for (int t = 0; t < 5; ++t) {
      int col = t * 16 + li;
      float x = accs[t][r] * 0.125f;
      bool ok = (col < S) && (col <= row);
      v[t] = ok ? x : -1e30f;
      mx = fmaxf(mx, v[t]);
    }
#pragma unroll
    for (int off = 1; off < 16; off <<= 1) mx = fmaxf(mx, __shfl_xor(mx, off, 64));
    float sum = 0.f;
#pragma unroll
    for (int t = 0; t < 5; ++t) {
      v[t] = (v[t] > -1e29f) ? __expf(v[t] - mx) : 0.f;
      sum += v[t];
    }
#pragma unroll
    for (int off = 1; off < 16; off <<= 1) sum += __shfl_xor(sum, off, 64);
    float inv = __fdividef(1.f, sum);
#pragma unroll
    for (int t = 0; t < 5; ++t) {
      int c = t * 16 + li;
      Pf[w][((c >> 3) * 16 + (row - w * 16)) * 8 + (c & 7)] = f2bf(v[t] * inv);
    }
  }
  for (int z = lane; z < 256; z += 64) {
    int kb = 10 + (z >> 7);
    int rem = z & 127;
    Pf[w][(kb * 16 + (rem >> 3)) * 8 + (rem & 7)] = 0;
  }
  f32x4 acco[4] = {};
#pragma unroll
  for (int s = 0; s < 3; ++s) {
    short8 ap = *(const short8*)(Pf[w] + ((s * 4 + lg) * 16 + li) * 8);
#pragma unroll
    for (int n = 0; n < 4; ++n) {
      short8 bv = *(const short8*)(Vt + ((n * 12 + s * 4 + lg) * 16 + li) * 8);
      acco[n] = __builtin_amdgcn_mfma_f32_16x16x32_bf16(ap, bv, acco[n], 0, 0, 0);
    }
  }
#pragma unroll
  for (int n = 0; n < 4; ++n)
#pragma unroll
    for (int r = 0; r < 4; ++r) {
      int row = rowg + r;
      if (row < S) O[(size_t)(base + row) * 512 + h * 64 + n * 16 + li] = f2bf(acco[n][r]);
    }
}

// ---------------- agg attention (fp32 math, S=9): QKV f32 in, bf16 out ----------------
__global__ __launch_bounds__(256) void attn_k(const float* __restrict__ qkv,
                                              short* __restrict__ O, int S, int causal) {
  int blk = blockIdx.x;
  int p = blk >> 3, h = blk & 7;
  __shared__ float Qs[Ltok][68], Ks[Ltok][68], Vs[Ltok][68];
  __shared__ float ps[4][132];
  int base = p * S;
  for (int idx = TID; idx < S * 16; idx += 256) {
    int j = idx >> 4, c = idx & 15;
    const float4* q = (const float4*)(qkv + (size_t)(base + j) * 1536 + h * 64);
    const float4* k = (const float4*)(qkv + (size_t)(base + j) * 1536 + 512 + h * 64);
    const float4* v = (const float4*)(qkv + (size_t)(base + j) * 1536 + 1024 + h * 64);
    ((float4*)&Qs[j][0])[c] = q[c];
    ((float4*)&Ks[j][0])[c] = k[c];
    ((float4*)&Vs[j][0])[c] = v[c];
  }
  __syncthreads();
  int wave = TID >> 6, lane = TID & 63;
  bool val0 = lane < S, val1 = lane + 64 < S;
  int j0 = val0 ? lane : 0;
  int j1 = val1 ? lane + 64 : 0;
  const float4* k0p = (const float4*)&Ks[j0][0];
  const float4* k1p = (const float4*)&Ks[j1][0];
  for (int i = wave; i < S; i += 4) {
    const float4* q4 = (const float4*)&Qs[i][0];
    float a0 = 0.f, a1 = 0.f;
#pragma unroll
    for (int d4 = 0; d4 < 16; ++d4) {
      float4 qv = q4[d4], k0v = k0p[d4], k1v = k1p[d4];
      a0 += qv.x * k0v.x + qv.y * k0v.y + qv.z * k0v.z + qv.w * k0v.w;
      a1 += qv.x * k1v.x + qv.y * k1v.y + qv.z * k1v.z + qv.w * k1v.w;
    }
    float m0 = (val0 && (!causal || lane <= i)) ? a0 * 0.125f : -1e30f;
    float m1 = (val1 && (!causal || lane + 64 <= i)) ? a1 * 0.125f : -1e30f;
    float mx = fmaxf(m0, m1);
#pragma unroll
    for (int off = 32; off; off >>= 1) mx = fmaxf(mx, __shfl_xor(mx, off, 64));
    float e0 = expf(m0 - mx), e1 = expf(m1 - mx);
    float sum = e0 + e1;
#pragma unroll
    for (int off = 32; off; off >>= 1) sum += __shfl_xor(sum, off, 64);
    float inv = 1.f / sum;
    ps[wave][lane] = e0 * inv;
    ps[wave][lane + 64] = e1 * inv;
    float o = 0.f;
    for (int j = 0; j < S; ++j) o += ps[wave][j] * Vs[j][lane];
    O[(base + i) * Dm + h * 64 + lane] = f2bf(o);
  }
}

// ---------------- final LN + eos gather + text_proj + L2 normalize (fp32) ----------------
__global__ __launch_bounds__(256) void feats_k(const float* __restrict__ X,
                                               const int* __restrict__ eosl,
                                               const float* __restrict__ g,
                                               const float* __restrict__ bb,
                                               const float* __restrict__ proj,
                                               float* __restrict__ feats, int p0) {
  int pl = blockIdx.x;
  int p = p0 + pl;
  int e = eosl[p];
  const float* x = X + (size_t)(pl * Ltok + e) * Dm;
  __shared__ float row[Dm];
  __shared__ float s1[256], s2[256];
  float v0 = x[TID], v1 = x[TID + 256];
  s1[TID] = v0 + v1;
  s2[TID] = v0 * v0 + v1 * v1;
  __syncthreads();
  for (int s = 128; s; s >>= 1) {
    if (TID < s) { s1[TID] += s1[TID + s]; s2[TID] += s2[TID + s]; }
    __syncthreads();
  }
  float mean = s1[0] * (1.f / 512.f);
  float var = s2[0] * (1.f / 512.f) - mean * mean;
  float inv = rsqrtf(var + 1e-5f);
  row[TID] = (v0 - mean) * inv * g[TID] + bb[TID];
  row[TID + 256] = (v1 - mean) * inv * g[TID + 256] + bb[TID + 256];
  __syncthreads();
  float a0 = 0.f, a1 = 0.f;
  for (int d = 0; d < Dm; ++d) {
    float r = row[d];
    a0 += r * proj[d * Dm + TID];
    a1 += r * proj[d * Dm + TID + 256];
  }
  s1[TID] = a0 * a0 + a1 * a1;
  __syncthreads();
  for (int s = 128; s; s >>= 1) { if (TID < s) s1[TID] += s1[TID + s]; __syncthreads(); }
  float sc = 1.f / sqrtf(s1[0]);
  feats[p * Dm + TID] = a0 * sc;
  feats[p * Dm + TID + 256] = a1 * sc;
}

// ---------------- rerank + fuse + scatter ----------------
__global__ void rerank_k(const float* __restrict__ sampled, const float* __restrict__ feats,
                         const int* __restrict__ selidx, const int* __restrict__ topk,
                         const float* __restrict__ logits, float* __restrict__ out1,
                         float* __restrict__ out3) {
  int idx = blockIdx.x;
  int s = idx / KTOP;
  int lane = TID;
  float acc = 0.f;
  for (int d = lane; d < Dm; d += 64) acc += sampled[s * Dm + d] * feats[idx * Dm + d];
#pragma unroll
  for (int off = 32; off; off >>= 1) acc += __shfl_down(acc, off, 64);
  if (lane == 0) {
    out1[idx] = acc;
    int row = selidx[s];
    int cls = topk[idx];
    float sl = logits[row * C1 + cls];
    float a = sigf(sl), b = sigf(acc);
    float fused = powf(a, 0.75f) * powf(b, 0.25f);
    float xx = fminf(fmaxf(fused, 0.f), 1.f);
    float x1 = fmaxf(xx, 1e-5f);
    float x2 = fmaxf(1.f - xx, 1e-5f);
    out3[row * C1 + cls] = logf(x1 / x2);
  }
}

// ============================ host ============================
static inline size_t alup(size_t x) { return (x + 255) & ~(size_t)255; }

constexpr size_t WT_QKV = (size_t)NL * Dm * 3 * Dm;
constexpr size_t WT_OUT = (size_t)NL * Dm * Dm;
constexpr size_t WT_FC  = (size_t)NL * Dm * MLPD;
constexpr size_t WT_PR  = (size_t)NL * MLPD * Dm;
constexpr size_t WT_ALL = WT_QKV + WT_OUT + WT_FC + WT_PR;
constexpr size_t MAGG   = (size_t)Pn * 9;  // 1440

static void plan_rows(int PC, size_t* rows_o, size_t* RP_o) {
  size_t rows = (size_t)PC * Ltok;
  if (rows < MAGG) rows = MAGG;
  size_t RP = (rows + 255) & ~(size_t)255;
  *rows_o = rows; *RP_o = RP;
}

static size_t plan_bytes(int PC) {
  size_t rows, RP;
  plan_rows(PC, &rows, &RP);
  size_t tot = 0;
  tot += alup(Bsz * Dm * 4);                  // h
  tot += alup(Bsz * 8);                       // entropy
  tot += alup(KSEL * 4);                      // selidx
  tot += alup(Pn * 4);                        // topk
  tot += alup(Pn * 4);                        // eosl
  tot += alup(KSEL * Dm * 4);                 // hsel
  tot += alup(KSEL * Dm * 4);                 // sampled
  tot += alup(Pn * NINS * Dm * 4);            // insbuf
  tot += alup(Pn * Dm * 4);                   // feats
  tot += alup(rows * Dm * 4);                 // X f32
  tot += alup(RP * Dm * 2);                   // Abuf bf16
  tot += alup(RP * Dm * 2);                   // Obuf bf16
  tot += alup(MAGG * 3 * Dm * 4);             // QKV f32 (agg only)
  tot += alup(RP * 3 * Dm * 2);               // QKVb bf16 (txt)
  tot += alup(RP * MLPD * 2);                 // Hb bf16
  tot += 2 * alup(WT_ALL * 2);                // bf16 weights (agg + txt)
  tot += alup((size_t)8 * Bsz * Dm * 4);      // P_lin
  tot += alup((size_t)4 * Bsz * C1 * 4);      // P_zs
  tot += alup((size_t)8 * KSEL * Dm * 4);     // P_smp
  tot += alup((size_t)16 * MAGG * Dm * 4);    // P_sk (agg split-K, S<=16)
  return tot;
}

extern "C" void kernel_launch(void* const* d_in, const int* in_sizes, int n_in,
                              void* d_out, int out_size, void* d_ws, size_t ws_size,
                              hipStream_t stream) {
  const float* x         = (const float*)d_in[0];
  const float* linear_w  = (const float*)d_in[1];
  const float* linear_b  = (const float*)d_in[2];
  const float* zs_w      = (const float*)d_in[3];
  const float* sample_w  = (const float*)d_in[4];
  const float* sample_b  = (const float*)d_in[5];
  const float* ins_token = (const float*)d_in[6];
  const float* token_seq = (const float*)d_in[7];
  const float* exemplar  = (const float*)d_in[8];
  const int*   eos_index = (const int*)d_in[9];
  const float* agg_ln1_g = (const float*)d_in[10];
  const float* agg_ln1_b = (const float*)d_in[11];
  const float* agg_qkv_w = (const float*)d_in[12];
  const float* agg_qkv_b = (const float*)d_in[13];
  const float* agg_out_w = (const float*)d_in[14];
  const float* agg_out_b = (const float*)d_in[15];
  const float* agg_ln2_g = (const float*)d_in[16];
  const float* agg_ln2_b = (const float*)d_in[17];
  const float* agg_fc_w  = (const float*)d_in[18];
  const float* agg_fc_b  = (const float*)d_in[19];
  const float* agg_pr_w  = (const float*)d_in[20];
  const float* agg_pr_b  = (const float*)d_in[21];
  const float* pos_emb   = (const float*)d_in[22];
  const float* txt_ln1_g = (const float*)d_in[23];
  const float* txt_ln1_b = (const float*)d_in[24];
  const float* txt_qkv_w = (const float*)d_in[25];
  const float* txt_qkv_b = (const float*)d_in[26];
  const float* txt_out_w = (const float*)d_in[27];
  const float* txt_out_b = (const float*)d_in[28];
  const float* txt_ln2_g = (const float*)d_in[29];
  const float* txt_ln2_b = (const float*)d_in[30];
  const float* txt_fc_w  = (const float*)d_in[31];
  const float* txt_fc_b  = (const float*)d_in[32];
  const float* txt_pr_w  = (const float*)d_in[33];
  const float* txt_pr_b  = (const float*)d_in[34];
  const float* lnf_g     = (const float*)d_in[35];
  const float* lnf_b     = (const float*)d_in[36];
  const float* text_proj = (const float*)d_in[37];

  float* out0 = (float*)d_out;
  float* out1 = out0 + Bsz * C1;
  float* out2 = out1 + KSEL * KTOP;
  float* out3 = out2 + KSEL;

  int PC = 20;
  const int cands[4] = {160, 80, 40, 20};
  for (int i = 0; i < 4; ++i)
    if (plan_bytes(cands[i]) <= ws_size) { PC = cands[i]; break; }
  int NC = Pn / PC;

  char* wp = (char*)d_ws;
  auto carve = [&](size_t bytes) -> void* { void* r = (void*)wp; wp += alup(bytes); return r; };
  size_t rows, RP;
  plan_rows(PC, &rows, &RP);

  float* h       = (float*)carve(Bsz * Dm * 4);
  double* ent    = (double*)carve(Bsz * 8);
  int* selidx    = (int*)carve(KSEL * 4);
  int* topk      = (int*)carve(Pn * 4);
  int* eosl      = (int*)carve(Pn * 4);
  float* hsel    = (float*)carve(KSEL * Dm * 4);
  float* sampled = (float*)carve(KSEL * Dm * 4);
  float* insbuf  = (float*)carve(Pn * NINS * Dm * 4);
  float* feats   = (float*)carve(Pn * Dm * 4);
  float* X       = (float*)carve(rows * Dm * 4);
  short* Abuf    = (short*)carve(RP * Dm * 2);
  short* Obuf    = (short*)carve(RP * Dm * 2);
  float* QKV     = (float*)carve(MAGG * 3 * Dm * 4);
  short* QKVb    = (short*)carve(RP * 3 * Dm * 2);
  short* Hb      = (short*)carve(RP * MLPD * 2);
  short* wtA     = (short*)carve(WT_ALL * 2);
  short* wtT     = (short*)carve(WT_ALL * 2);
  float* Plin    = (float*)carve((size_t)8 * Bsz * Dm * 4);
  float* Pzs     = (float*)carve((size_t)4 * Bsz * C1 * 4);
  float* Psmp    = (float*)carve((size_t)8 * KSEL * Dm * 4);
  float* Psk     = (float*)carve((size_t)16 * MAGG * Dm * 4);

  short* wtA_qkv = wtA;
  short* wtA_out = wtA_qkv + WT_QKV;
  short* wtA_fc  = wtA_out + WT_OUT;
  short* wtA_pr  = wtA_fc + WT_FC;
  short* wtT_qkv = wtT;
  short* wtT_out = wtT_qkv + WT_QKV;
  short* wtT_fc  = wtT_out + WT_OUT;
  short* wtT_pr  = wtT_fc + WT_FC;

  dim3 blk(256);
  auto wconv = [&](const float* W, short* Wt, int K, int N) {
    dim3 g(N / 32, K / 32, NL);
    wconv_k<<<g, blk, 0, stream>>>(W, Wt, K, N);
  };
  auto bgemm = [&](const short* A, const short* Wt, const float* bias, float* Cf, short* Cb,
                   float* Xres, int M, int N, int K, int mode) {
    if (M >= 2048 && N >= 1536) {
      dim3 g(N / 128, (M + 255) / 256);
      bgemm_tall_k<<<g, dim3(512), 0, stream>>>(A, Wt, bias, Cf, Cb, Xres, M, N, K, mode);
    } else if (M >= 2048 && N < 1536 && (K & 127) == 0) {
      // occupancy-starved grid (few col-blocks): BK=128 halves steps, LDS not binding
      dim3 g(N / 128, (M + 127) / 128);
      bgemm_k128<<<g, blk, 0, stream>>>(A, Wt, bias, Cf, Cb, Xres, M, N, K, mode);
    } else {
      dim3 g(N / 128, (M + 127) / 128);
      bgemm_k<<<g, blk, 0, stream>>>(A, Wt, bias, Cf, Cb, Xres, M, N, K, mode);
    }
  };
  // split-K residual GEMM (agg starved cases): partials + deterministic reduce
  auto bgemm_res_sk = [&](const short* A, const short* Wt, const float* bias, float* Xres,
                          int M, int N, int K, int S) {
    dim3 g(N / 128, (M + 127) / 128, S);
    bgemm_sk_k<<<g, blk, 0, stream>>>(A, Wt, Psk, M, N, K, K / S);
    int MN = M * N;
    reduce_res_k<<<(MN + 255) / 256, blk, 0, stream>>>(Psk, bias, Xres, MN, N, S);
  };
  auto gemm32s = [&](const float* A, const float* W, float* P, int M, int N, int K, int S) {
    dim3 g((N + 63) / 64, (M + 63) / 64, S);
    gemm32s_k<<<g, blk, 0, stream>>>(A, W, P, M, N, K, K / S);
  };
  auto reduce = [&](const float* P, const float* bias, float* C, float* C2, int MN, int N, int S) {
    reduce_k<<<(MN + 255) / 256, blk, 0, stream>>>(P, bias, C, C2, MN, N, S);
  };
  auto ln = [&](const float* Xp, const float* g, const float* b, short* A, int M) {
    ln_k<<<M / 2, blk, 0, stream>>>(Xp, g, b, A);
  };

  // ---- weight preconvert+transpose (bf16 [N,K]) ----
  wconv(agg_qkv_w, wtA_qkv, Dm, 3 * Dm);
  wconv(agg_out_w, wtA_out, Dm, Dm);
  wconv(agg_fc_w,  wtA_fc,  Dm, MLPD);
  wconv(agg_pr_w,  wtA_pr,  MLPD, Dm);
  wconv(txt_qkv_w, wtT_qkv, Dm, 3 * Dm);
  wconv(txt_out_w, wtT_out, Dm, Dm);
  wconv(txt_fc_w,  wtT_fc,  Dm, MLPD);
  wconv(txt_pr_w,  wtT_pr,  MLPD, Dm);

  // ---- base classifier (fp32 split-K, exact/deterministic) ----
  gemm32s(x, linear_w, Plin, Bsz, Dm, DIN, 8);
  reduce(Plin, linear_b, h, nullptr, Bsz * Dm, Dm, 8);
  rownorm_k<<<Bsz, blk, 0, stream>>>(h);
  gemm32s(h, zs_w, Pzs, Bsz, C1, Dm, 4);
  reduce(Pzs, nullptr, out0, out3, Bsz * C1, C1, 4);
  entropy_k<<<Bsz, blk, 0, stream>>>(out0, ent);
  top32_k<<<1, blk, 0, stream>>>(ent, selidx, out2);
  top5_k<<<KSEL, blk, 0, stream>>>(out0, selidx, topk);
  eos_k<<<1, blk, 0, stream>>>(eos_index, topk, eosl);
  gather_h_k<<<KSEL, blk, 0, stream>>>(h, selidx, hsel);
  gemm32s(hsel, sample_w, Psmp, KSEL, Dm, Dm, 8);
  reduce(Psmp, sample_b, sampled, nullptr, KSEL * Dm, Dm, 8);

  // ---- aggregator transformer (S=9, 160 seqs, no mask; fp32 attention) ----
  build_agg_k<<<Pn * 9, blk, 0, stream>>>(ins_token, sampled, exemplar, topk, X);
  {
    int M = (int)MAGG;  // 1440
    for (int i = 0; i < NL; ++i) {
      ln(X, agg_ln1_g + i * Dm, agg_ln1_b + i * Dm, Abuf, M);
      bgemm(Abuf, wtA_qkv + (size_t)i * Dm * 3 * Dm, agg_qkv_b + i * 3 * Dm, QKV, nullptr, nullptr, M, 3 * Dm, Dm, 0);
      attn_k<<<Pn * NHEAD, blk, 0, stream>>>(QKV, Obuf, 9, 0);
      bgemm_res_sk(Obuf, wtA_out + (size_t)i * Dm * Dm, agg_out_b + i * Dm, X, M, Dm, Dm, 8);
      ln(X, agg_ln2_g + i * Dm, agg_ln2_b + i * Dm, Abuf, M);
      bgemm(Abuf, wtA_fc + (size_t)i * Dm * MLPD, agg_fc_b + i * MLPD, nullptr, Hb, nullptr, M, MLPD, Dm, 2);
      bgemm_res_sk(Hb, wtA_pr + (size_t)i * MLPD * Dm, agg_pr_b + i * Dm, X, M, Dm, MLPD, 16);
    }
  }
  save_ins_k<<<Pn, blk, 0, stream>>>(X, insbuf);

  // ---- text transformer (S=77, causal; MFMA attention), chunked over sequences ----
  for (int c = 0; c < NC; ++c) {
    int p0 = c * PC;
    int M = PC * Ltok;
    build_txt_k<<<PC * Ltok, blk, 0, stream>>>(token_seq, insbuf, pos_emb, topk, X, p0);
    for (int i = 0; i < NL; ++i) {
      ln(X, txt_ln1_g + i * Dm, txt_ln1_b + i * Dm, Abuf, M);
      bgemm(Abuf, wtT_qkv + (size_t)i * Dm * 3 * Dm, txt_qkv_b + i * 3 * Dm, nullptr, QKVb, nullptr, M, 3 * Dm, Dm, 3);
      attn_tx_k<<<dim3(PC * NHEAD), dim3(320), 0, stream>>>(QKVb, Obuf, Ltok);
      bgemm(Obuf, wtT_out + (size_t)i * Dm * Dm, txt_out_b + i * Dm, nullptr, nullptr, X, M, Dm, Dm, 1);
      ln(X, txt_ln2_g + i * Dm, txt_ln2_b + i * Dm, Abuf, M);
      bgemm(Abuf, wtT_fc + (size_t)i * Dm * MLPD, txt_fc_b + i * MLPD, nullptr, Hb, nullptr, M, MLPD, Dm, 2);
      bgemm(Hb, wtT_pr + (size_t)i * MLPD * Dm, txt_pr_b + i * Dm, nullptr, nullptr, X, M, Dm, MLPD, 1);
    }
    feats_k<<<PC, blk, 0, stream>>>(X, eosl, lnf_g, lnf_b, text_proj, feats, p0);
  }

  // ---- rerank + fuse + scatter ----
  rerank_k<<<Pn, dim3(64), 0, stream>>>(sampled, feats, selidx, topk, out0, out1, out3);
}

// Round 15
// 1811.667 us; speedup vs baseline: 1.0424x; 1.0424x over previous
//
#include <hip/hip_runtime.h>
#include <math.h>

#define TID ((int)threadIdx.x)

// problem sizes
constexpr int Bsz = 1000, DIN = 1024, Dm = 512, C1 = 1204, C0 = 1203, Ltok = 77;
constexpr int NINS = 4, NEX = 5, KSEL = 32, KTOP = 5, NHEAD = 8, DH = 64, MLPD = 2048, NL = 4, Pn = 160;
constexpr float TEMPc = 50.0f;

typedef __attribute__((ext_vector_type(8))) short short8;
typedef __attribute__((ext_vector_type(4))) float f32x4;
typedef __attribute__((address_space(1))) const void g1void;
typedef __attribute__((address_space(3))) void l3void;
#define GLOAD16(g, l) __builtin_amdgcn_global_load_lds((g1void*)(g), (l3void*)(l), 16, 0, 0)

__device__ __forceinline__ float sigf(float z) {  // accurate (rerank path)
  return z >= 0.f ? 1.f / (1.f + expf(-z)) : expf(z) / (1.f + expf(z));
}

__device__ __forceinline__ float qgelu(float v) {  // fast quickgelu (bgemm epilogue)
  return v * __fdividef(1.f, 1.f + __expf(-1.702f * v));
}

__device__ __forceinline__ unsigned short f2bfu(float f) {  // round-to-nearest-even
  unsigned u = __builtin_bit_cast(unsigned, f);
  u += 0x7fffu + ((u >> 16) & 1u);
  return (unsigned short)(u >> 16);
}
__device__ __forceinline__ short f2bf(float f) { return (short)f2bfu(f); }

__device__ __forceinline__ void epi_store(f32x4 v, const float* bias, int colb, size_t off,
                                          int mode, float* Cf, short* Cb, float* Xres) {
  if (bias) {
    float4 bv = *(const float4*)(bias + colb);
    v[0] += bv.x; v[1] += bv.y; v[2] += bv.z; v[3] += bv.w;
  }
  if (mode == 0) {
    *(float4*)(Cf + off) = make_float4(v[0], v[1], v[2], v[3]);
  } else if (mode == 1) {
    float4* p = (float4*)(Xres + off);
    float4 o = *p;
    o.x += v[0]; o.y += v[1]; o.z += v[2]; o.w += v[3];
    *p = o;
  } else {
    if (mode == 2) {
      v[0] = qgelu(v[0]); v[1] = qgelu(v[1]); v[2] = qgelu(v[2]); v[3] = qgelu(v[3]);
    }
    uint2 pk;
    pk.x = (unsigned)f2bfu(v[0]) | ((unsigned)f2bfu(v[1]) << 16);
    pk.y = (unsigned)f2bfu(v[2]) | ((unsigned)f2bfu(v[3]) << 16);
    *(uint2*)(Cb + off) = pk;
  }
}

// ================= bf16 MFMA GEMM (128x128, BK=64): C = A @ Wt^T + bias =================
// R9 config (best measured): single 32KB LDS buffer, 4 blocks/CU, BK=64.
__global__ __launch_bounds__(256, 4) void bgemm_k(const short* __restrict__ A,
                                                  const short* __restrict__ Bt,
                                                  const float* __restrict__ bias,
                                                  float* __restrict__ Cf,
                                                  short* __restrict__ Cb,
                                                  float* __restrict__ Xres,
                                                  int M, int N, int K, int mode) {
  __shared__ short As[8192];  // 128 rows x 64 k (two 32-k subtiles)
  __shared__ short Bs[8192];
  int nwg = gridDim.x * gridDim.y;
  int orig = blockIdx.y * gridDim.x + blockIdx.x;
  int xcd = orig & 7, lid = orig >> 3;
  int q = nwg >> 3, r = nwg & 7;
  int swz = (xcd < r ? xcd * (q + 1) : r * (q + 1) + (xcd - r) * q) + lid;
  int row0 = (swz / gridDim.x) * 128, col0 = (swz % gridDim.x) * 128;
  int lane = TID & 63;
  int w = TID >> 6;
  int wr = (TID >> 7) & 1, wc = (TID >> 6) & 1;
  int skb = (TID >> 4) & 3, si = TID & 15;
  f32x4 acc[4][4] = {};
  int nt = K >> 6;
  int kb = lane >> 4, i = lane & 15;
  for (int t = 0; t < nt; ++t) {
#pragma unroll
    for (int s = 0; s < 2; ++s) {
#pragma unroll
      for (int c = 0; c < 2; ++c) {
        int row = (c * 4 + w) * 16 + si;
        int k0 = (t << 6) + (s << 5) + skb * 8;
        GLOAD16(A + (size_t)(row0 + row) * K + k0, As + s * 4096 + (c * 256 + w * 64) * 8);
        GLOAD16(Bt + (size_t)(col0 + row) * K + k0, Bs + s * 4096 + (c * 256 + w * 64) * 8);
      }
    }
    __syncthreads();
#pragma unroll
    for (int s = 0; s < 2; ++s) {
      const short* Ab = As + s * 4096;
      const short* Bb = Bs + s * 4096;
      short8 af[4], bfr[4];
#pragma unroll
      for (int m = 0; m < 4; ++m)
        af[m] = *(const short8*)(Ab + ((((wr * 4 + m) * 4 + kb) * 16 + i) * 8));
#pragma unroll
      for (int n = 0; n < 4; ++n)
        bfr[n] = *(const short8*)(Bb + ((((wc * 4 + n) * 4 + kb) * 16 + i) * 8));
#pragma unroll
      for (int m = 0; m < 4; ++m)
#pragma unroll
        for (int n = 0; n < 4; ++n)
          acc[m][n] = __builtin_amdgcn_mfma_f32_16x16x32_bf16(bfr[n], af[m], acc[m][n], 0, 0, 0);
    }
    __syncthreads();
  }
  int li = lane & 15, lg = lane >> 4;
#pragma unroll
  for (int m = 0; m < 4; ++m) {
    int row = row0 + wr * 64 + m * 16 + li;
    if (row >= M) continue;
#pragma unroll
    for (int n = 0; n < 4; ++n) {
      int colb = col0 + wc * 64 + n * 16 + lg * 4;
      epi_store(acc[m][n], bias, colb, (size_t)row * N + colb, mode, Cf, Cb, Xres);
    }
  }
}

// ========== tall bf16 MFMA GEMM (256x128, 512 thr, BK=64) — txt qkv/fc routing ==========
__global__ __launch_bounds__(512, 4) void bgemm_tall_k(const short* __restrict__ A,
                                                       const short* __restrict__ Bt,
                                                       const float* __restrict__ bias,
                                                       float* __restrict__ Cf,
                                                       short* __restrict__ Cb,
                                                       float* __restrict__ Xres,
                                                       int M, int N, int K, int mode) {
  __shared__ short As[16384];
  __shared__ short Bs[8192];
  int nwg = gridDim.x * gridDim.y;
  int orig = blockIdx.y * gridDim.x + blockIdx.x;
  int xcd = orig & 7, lid = orig >> 3;
  int q = nwg >> 3, r = nwg & 7;
  int swz = (xcd < r ? xcd * (q + 1) : r * (q + 1) + (xcd - r) * q) + lid;
  int row0 = (swz / gridDim.x) * 256, col0 = (swz % gridDim.x) * 128;
  int lane = TID & 63;
  int w = TID >> 6;
  int wr = w >> 1, wc = w & 1;
  f32x4 acc[4][4] = {};
  int nt = K >> 6;
  int kb = lane >> 4, i = lane & 15;
  int sg0 = TID >> 6, skb = (TID >> 4) & 3, si = TID & 15;
  for (int t = 0; t < nt; ++t) {
#pragma unroll
    for (int s = 0; s < 2; ++s) {
      int k0 = (t << 6) + (s << 5) + skb * 8;
#pragma unroll
      for (int c0 = 0; c0 < 2; ++c0) {
        int row = (c0 * 8 + sg0) * 16 + si;
        GLOAD16(A + (size_t)(row0 + row) * K + k0, As + s * 8192 + (c0 * 512 + TID) * 8);
      }
      {
        int row = sg0 * 16 + si;
        GLOAD16(Bt + (size_t)(col0 + row) * K + k0, Bs + s * 4096 + TID * 8);
      }
    }
    __syncthreads();
#pragma unroll
    for (int s = 0; s < 2; ++s) {
      const short* Ab = As + s * 8192;
      const short* Bb = Bs + s * 4096;
      short8 af[4], bfr[4];
#pragma unroll
      for (int m = 0; m < 4; ++m)
        af[m] = *(const short8*)(Ab + ((((wr * 4 + m) * 4 + kb) * 16 + i) * 8));
#pragma unroll
      for (int n = 0; n < 4; ++n)
        bfr[n] = *(const short8*)(Bb + ((((wc * 4 + n) * 4 + kb) * 16 + i) * 8));
#pragma unroll
      for (int m = 0; m < 4; ++m)
#pragma unroll
        for (int n = 0; n < 4; ++n)
          acc[m][n] = __builtin_amdgcn_mfma_f32_16x16x32_bf16(bfr[n], af[m], acc[m][n], 0, 0, 0);
    }
    __syncthreads();
  }
  int li = lane & 15, lg = lane >> 4;
#pragma unroll
  for (int m = 0; m < 4; ++m) {
    int row = row0 + wr * 64 + m * 16 + li;
    if (row >= M) continue;
#pragma unroll
    for (int n = 0; n < 4; ++n) {
      int colb = col0 + wc * 64 + n * 16 + lg * 4;
      epi_store(acc[m][n], bias, colb, (size_t)row * N + colb, mode, Cf, Cb, Xres);
    }
  }
}

// ======== split-K bf16 MFMA GEMM: P[z][M][N] partials (agg starved GEMMs) ========
__global__ __launch_bounds__(256, 4) void bgemm_sk_k(const short* __restrict__ A,
                                                     const short* __restrict__ Bt,
                                                     float* __restrict__ P,
                                                     int M, int N, int K, int KC) {
  __shared__ short As[8192];
  __shared__ short Bs[8192];
  int nwg = gridDim.x * gridDim.y;
  int orig = blockIdx.y * gridDim.x + blockIdx.x;
  int xcd = orig & 7, lid = orig >> 3;
  int q = nwg >> 3, r = nwg & 7;
  int swz = (xcd < r ? xcd * (q + 1) : r * (q + 1) + (xcd - r) * q) + lid;
  int row0 = (swz / gridDim.x) * 128, col0 = (swz % gridDim.x) * 128;
  int kbeg = blockIdx.z * KC;
  int lane = TID & 63;
  int w = TID >> 6;
  int wr = (TID >> 7) & 1, wc = (TID >> 6) & 1;
  int skb = (TID >> 4) & 3, si = TID & 15;
  f32x4 acc[4][4] = {};
  int nt = KC >> 6;
  int kb = lane >> 4, i = lane & 15;
  for (int t = 0; t < nt; ++t) {
#pragma unroll
    for (int s = 0; s < 2; ++s) {
#pragma unroll
      for (int c = 0; c < 2; ++c) {
        int row = (c * 4 + w) * 16 + si;
        int k0 = kbeg + (t << 6) + (s << 5) + skb * 8;
        GLOAD16(A + (size_t)(row0 + row) * K + k0, As + s * 4096 + (c * 256 + w * 64) * 8);
        GLOAD16(Bt + (size_t)(col0 + row) * K + k0, Bs + s * 4096 + (c * 256 + w * 64) * 8);
      }
    }
    __syncthreads();
#pragma unroll
    for (int s = 0; s < 2; ++s) {
      const short* Ab = As + s * 4096;
      const short* Bb = Bs + s * 4096;
      short8 af[4], bfr[4];
#pragma unroll
      for (int m = 0; m < 4; ++m)
        af[m] = *(const short8*)(Ab + ((((wr * 4 + m) * 4 + kb) * 16 + i) * 8));
#pragma unroll
      for (int n = 0; n < 4; ++n)
        bfr[n] = *(const short8*)(Bb + ((((wc * 4 + n) * 4 + kb) * 16 + i) * 8));
#pragma unroll
      for (int m = 0; m < 4; ++m)
#pragma unroll
        for (int n = 0; n < 4; ++n)
          acc[m][n] = __builtin_amdgcn_mfma_f32_16x16x32_bf16(bfr[n], af[m], acc[m][n], 0, 0, 0);
    }
    __syncthreads();
  }
  float* Pz = P + (size_t)blockIdx.z * M * N;
  int li = lane & 15, lg = lane >> 4;
#pragma unroll
  for (int m = 0; m < 4; ++m) {
    int row = row0 + wr * 64 + m * 16 + li;
    if (row >= M) continue;
#pragma unroll
    for (int n = 0; n < 4; ++n) {
      int colb = col0 + wc * 64 + n * 16 + lg * 4;
      *(float4*)(Pz + (size_t)row * N + colb) = make_float4(acc[m][n][0], acc[m][n][1], acc[m][n][2], acc[m][n][3]);
    }
  }
}

// reduce split-K partials into residual: Xres[i] += sum_s P[s][i] + bias[i % N]
__global__ __launch_bounds__(256) void reduce_res_k(const float* __restrict__ P,
                                                    const float* __restrict__ bias,
                                                    float* __restrict__ Xres,
                                                    int MN, int N, int S) {
  int i = blockIdx.x * 256 + TID;
  if (i >= MN) return;
  float v = bias[i % N];
  for (int s = 0; s < S; ++s) v += P[(size_t)s * MN + i];
  Xres[i] += v;
}

// ============ weight convert+transpose: W[NL][K][N] f32 -> Wt[NL][N][K] bf16 ============
__global__ __launch_bounds__(256) void wconv_k(const float* __restrict__ W,
                                               short* __restrict__ Wt, int K, int N) {
  int l = blockIdx.z;
  const float* Wl = W + (size_t)l * K * N;
  short* Wtl = Wt + (size_t)l * K * N;
  __shared__ float t[32][33];
  int n0 = blockIdx.x * 32, k0 = blockIdx.y * 32;
  int tx = TID & 31, ty = TID >> 5;
#pragma unroll
  for (int u = 0; u < 4; ++u)
    t[ty + u * 8][tx] = Wl[(size_t)(k0 + ty + u * 8) * N + n0 + tx];
  __syncthreads();
#pragma unroll
  for (int u = 0; u < 4; ++u)
    Wtl[(size_t)(n0 + ty + u * 8) * K + k0 + tx] = f2bf(t[tx][ty + u * 8]);
}

// ---------------- fp32 split-K GEMM (classifier path, exact) ----------------
__global__ __launch_bounds__(256) void gemm32s_k(const float* __restrict__ A,
                                                 const float* __restrict__ W,
                                                 float* __restrict__ P,
                                                 int M, int N, int K, int KC) {
  __shared__ float As[64][17];
  __shared__ float Ws[16][65];
  int tx = TID & 15, ty = TID >> 4;
  int row0 = blockIdx.y * 64, col0 = blockIdx.x * 64;
  int kbeg = blockIdx.z * KC;
  int kend = kbeg + KC < K ? kbeg + KC : K;
  float acc[4][4] = {};
  for (int k0 = kbeg; k0 < kend; k0 += 16) {
    {
      int r = TID >> 2, c4 = (TID & 3) * 4;
      int gr = row0 + r;
#pragma unroll
      for (int u = 0; u < 4; ++u) {
        int gc = k0 + c4 + u;
        As[r][c4 + u] = (gr < M && gc < K) ? A[gr * K + gc] : 0.f;
      }
    }
    {
      int c = TID & 63;
      int gc = col0 + c;
#pragma unroll
      for (int u = 0; u < 4; ++u) {
        int rr = (TID >> 6) * 4 + u;
        int gk = k0 + rr;
        Ws[rr][c] = (gk < K && gc < N) ? W[gk * N + gc] : 0.f;
      }
    }
    __syncthreads();
#pragma unroll
    for (int kk = 0; kk < 16; ++kk) {
      float a[4], b[4];
#pragma unroll
      for (int i = 0; i < 4; ++i) a[i] = As[ty * 4 + i][kk];
#pragma unroll
      for (int j = 0; j < 4; ++j) b[j] = Ws[kk][tx * 4 + j];
#pragma unroll
      for (int i = 0; i < 4; ++i)
#pragma unroll
        for (int j = 0; j < 4; ++j) acc[i][j] += a[i] * b[j];
    }
    __syncthreads();
  }
  float* Ps = P + (size_t)blockIdx.z * M * N;
#pragma unroll
  for (int i = 0; i < 4; ++i) {
    int rrow = row0 + ty * 4 + i;
    if (rrow >= M) continue;
#pragma unroll
    for (int j = 0; j < 4; ++j) {
      int ccol = col0 + tx * 4 + j;
      if (ccol >= N) continue;
      Ps[(size_t)rrow * N + ccol] = acc[i][j];
    }
  }
}

__global__ __launch_bounds__(256) void reduce_k(const float* __restrict__ P,
                                                const float* __restrict__ bias,
                                                float* __restrict__ C,
                                                float* __restrict__ C2,
                                                int MN, int N, int S) {
  int i = blockIdx.x * 256 + TID;
  if (i >= MN) return;
  float v = 0.f;
  for (int s = 0; s < S; ++s) v += P[(size_t)s * MN + i];
  if (bias) v += bias[i % N];
  C[i] = v;
  if (C2) C2[i] = v;
}

// ---------------- row normalize: h = TEMP * h / ||h|| ----------------
__global__ __launch_bounds__(256) void rownorm_k(float* __restrict__ h) {
  int r = blockIdx.x;
  float* x = h + r * Dm;
  float v0 = x[TID], v1 = x[TID + 256];
  __shared__ float s1[256];
  s1[TID] = v0 * v0 + v1 * v1;
  __syncthreads();
  for (int s = 128; s; s >>= 1) { if (TID < s) s1[TID] += s1[TID + s]; __syncthreads(); }
  float sc = TEMPc / sqrtf(s1[0]);
  x[TID] = v0 * sc;
  x[TID + 256] = v1 * sc;
}

// ---------------- entropy (double accumulation, exact) ----------------
__global__ __launch_bounds__(256) void entropy_k(const float* __restrict__ logits,
                                                 double* __restrict__ ent) {
  int r = blockIdx.x;
  double acc = 0.0;
  for (int c = TID; c < C1; c += 256) {
    float z = logits[r * C1 + c];
    float ls = z >= 0.f ? -log1pf(expf(-z)) : z - log1pf(expf(z));
    float p = z >= 0.f ? 1.f / (1.f + expf(-z)) : expf(z) / (1.f + expf(z));
    acc += (double)(-p * ls);
  }
  __shared__ double sd[256];
  sd[TID] = acc;
  __syncthreads();
  for (int s = 128; s; s >>= 1) { if (TID < s) sd[TID] += sd[TID + s]; __syncthreads(); }
  if (TID == 0) ent[r] = sd[0];
}

// ---------------- top-32 over entropy[1000] (desc, ties -> lower idx) ----------------
__global__ __launch_bounds__(256) void top32_k(const double* __restrict__ ent,
                                               int* __restrict__ selidx,
                                               float* __restrict__ out2) {
  __shared__ double v[1000];
  __shared__ double wv[4];
  __shared__ int wi[4];
  for (int i = TID; i < 1000; i += 256) v[i] = ent[i];
  __syncthreads();
  int w = TID >> 6, lane = TID & 63;
  for (int r = 0; r < KSEL; ++r) {
    double bv = -1e300; int bi = 1 << 30;
    for (int i = TID; i < 1000; i += 256) {
      double x = v[i];
      if (x > bv || (x == bv && i < bi)) { bv = x; bi = i; }
    }
#pragma unroll
    for (int off = 32; off; off >>= 1) {
      double ov = __shfl_xor(bv, off, 64);
      int oi = __shfl_xor(bi, off, 64);
      if (ov > bv || (ov == bv && oi < bi)) { bv = ov; bi = oi; }
    }
    if (lane == 0) { wv[w] = bv; wi[w] = bi; }
    __syncthreads();
    if (TID == 0) {
      double fv = wv[0]; int fi = wi[0];
#pragma unroll
      for (int u = 1; u < 4; ++u)
        if (wv[u] > fv || (wv[u] == fv && wi[u] < fi)) { fv = wv[u]; fi = wi[u]; }
      selidx[r] = fi; out2[r] = (float)fi; v[fi] = -1e300;
    }
    __syncthreads();
  }
}

// ---------------- per-selected-row top-5 over first 1203 logits ----------------
__global__ __launch_bounds__(256) void top5_k(const float* __restrict__ logits,
                                              const int* __restrict__ selidx,
                                              int* __restrict__ topk) {
  int s = blockIdx.x;
  int row = selidx[s];
  __shared__ float v[C0];
  __shared__ float wv[4];
  __shared__ int wi[4];
  for (int i = TID; i < C0; i += 256) v[i] = logits[row * C1 + i];
  __syncthreads();
  int w = TID >> 6, lane = TID & 63;
  for (int r = 0; r < KTOP; ++r) {
    float bv = -INFINITY; int bi = 1 << 30;
    for (int i = TID; i < C0; i += 256) {
      float x = v[i];
      if (x > bv || (x == bv && i < bi)) { bv = x; bi = i; }
    }
#pragma unroll
    for (int off = 32; off; off >>= 1) {
      float ov = __shfl_xor(bv, off, 64);
      int oi = __shfl_xor(bi, off, 64);
      if (ov > bv || (ov == bv && oi < bi)) { bv = ov; bi = oi; }
    }
    if (lane == 0) { wv[w] = bv; wi[w] = bi; }
    __syncthreads();
    if (TID == 0) {
      float fv = wv[0]; int fi = wi[0];
#pragma unroll
      for (int u = 1; u < 4; ++u)
        if (wv[u] > fv || (wv[u] == fv && wi[u] < fi)) { fv = wv[u]; fi = wi[u]; }
      topk[s * KTOP + r] = fi; v[fi] = -INFINITY;
    }
    __syncthreads();
  }
}

__global__ void eos_k(const int* __restrict__ eos_index, const int* __restrict__ topk,
                      int* __restrict__ eosl) {
  for (int p = TID; p < Pn; p += 256) eosl[p] = eos_index[topk[p]] + 2 * NINS;
}

__global__ void gather_h_k(const float* __restrict__ h, const int* __restrict__ selidx,
                           float* __restrict__ hsel) {
  int s = blockIdx.x;
  int row = selidx[s];
  for (int d = TID; d < Dm; d += 256) hsel[s * Dm + d] = h[row * Dm + d];
}

// ---------------- build aggregator input [160,9,512] f32 ----------------
__global__ __launch_bounds__(256) void build_agg_k(const float* __restrict__ ins,
                                                   const float* __restrict__ sampled,
                                                   const float* __restrict__ ex,
                                                   const int* __restrict__ topk,
                                                   float* __restrict__ X) {
  int b = blockIdx.x;
  int p = b / 9, tok = b % 9;
  int s = p / KTOP;
#pragma unroll
  for (int u = 0; u < 2; ++u) {
    int d = TID + u * 256;
    float v;
    if (tok < NINS) v = ins[tok * Dm + d] + sampled[s * Dm + d] * (1.f / TEMPc);
    else {
      int cls = topk[p];
      v = ex[(cls * NEX + (tok - NINS)) * Dm + d];
    }
    X[b * Dm + d] = v;
  }
}

__global__ void save_ins_k(const float* __restrict__ X, float* __restrict__ insbuf) {
  int p = blockIdx.x;
  for (int i = TID; i < NINS * Dm; i += 256) insbuf[p * NINS * Dm + i] = X[p * 9 * Dm + i];
}

// ---------------- build txt input chunk (f32) ----------------
__global__ __launch_bounds__(256) void build_txt_k(const float* __restrict__ token_seq,
                                                   const float* __restrict__ insbuf,
                                                   const float* __restrict__ pos,
                                                   const int* __restrict__ topk,
                                                   float* __restrict__ X, int p0) {
  int b = blockIdx.x;
  int pl = b / Ltok, tok = b % Ltok;
  int p = p0 + pl;
  int cls = topk[p];
#pragma unroll
  for (int u = 0; u < 2; ++u) {
    int d = TID + u * 256;
    float v;
    if (tok < 2) v = token_seq[(cls * Ltok + tok) * Dm + d];
    else if (tok < 2 + NINS) v = insbuf[(p * NINS + (tok - 2)) * Dm + d];
    else v = token_seq[(cls * Ltok + (tok - NINS)) * Dm + d];
    X[b * Dm + d] = v + pos[tok * Dm + d];
  }
}

// ------- layernorm: f32 in -> bf16 out. 2 rows/block, float4 loads, packed stores -------
__global__ __launch_bounds__(256) void ln_k(const float* __restrict__ X,
                                            const float* __restrict__ g,
                                            const float* __restrict__ b,
                                            short* __restrict__ A) {
  int t = blockIdx.x * 2 + (TID >> 7);  // row
  int l = TID & 127;                    // 128 threads per row, 4 elems each
  const float* x = X + (size_t)t * Dm;
  float4 v = ((const float4*)x)[l];
  float s1 = v.x + v.y + v.z + v.w;
  float s2 = v.x * v.x + v.y * v.y + v.z * v.z + v.w * v.w;
#pragma unroll
  for (int off = 32; off; off >>= 1) {
    s1 += __shfl_xor(s1, off, 64);
    s2 += __shfl_xor(s2, off, 64);
  }
  __shared__ float w1[4], w2[4];
  int w = TID >> 6;
  if ((TID & 63) == 0) { w1[w] = s1; w2[w] = s2; }
  __syncthreads();
  int wb = (TID >> 7) << 1;
  float S1 = w1[wb] + w1[wb + 1];
  float S2 = w2[wb] + w2[wb + 1];
  float mean = S1 * (1.f / 512.f);
  float var = S2 * (1.f / 512.f) - mean * mean;
  float inv = rsqrtf(var + 1e-5f);
  float4 gv = ((const float4*)g)[l];
  float4 bv = ((const float4*)b)[l];
  uint2 pk;
  pk.x = (unsigned)f2bfu((v.x - mean) * inv * gv.x + bv.x) |
         ((unsigned)f2bfu((v.y - mean) * inv * gv.y + bv.y) << 16);
  pk.y = (unsigned)f2bfu((v.z - mean) * inv * gv.z + bv.z) |
         ((unsigned)f2bfu((v.w - mean) * inv * gv.w + bv.w) << 16);
  *(uint2*)(A + (size_t)t * Dm + l * 4) = pk;
}

// ======== txt attention, MFMA bf16: one block per (seq, head), 5 waves ========
__global__ __launch_bounds__(320) void attn_tx_k(const short* __restrict__ qkv,
                                                 short* __restrict__ O, int S) {
  __shared__ short Kf[5120];
  __shared__ short Vt[6144];
  __shared__ short Pf[5][1536];
  int p = blockIdx.x >> 3, h = blockIdx.x & 7;
  int base = p * S;
  for (int c = TID; c < 640; c += 320) {
    int i = c & 15, kb = (c >> 4) & 7, g = c >> 7;
    int j = g * 16 + i;
    short8 v = {};
    if (j < S) v = *(const short8*)(qkv + (size_t)(base + j) * 1536 + 512 + h * 64 + kb * 8);
    *(short8*)(Kf + c * 8) = v;
  }
  for (int c = TID; c < 640; c += 320) {
    int j = c >> 3;
    int d0 = (c & 7) * 8;
    short8 v = {};
    if (j < S) v = *(const short8*)(qkv + (size_t)(base + j) * 1536 + 1024 + h * 64 + d0);
    int kb = j >> 3, jj = j & 7;
#pragma unroll
    for (int u = 0; u < 8; ++u) {
      int d = d0 + u;
      Vt[(((d >> 4) * 12 + kb) * 16 + (d & 15)) * 8 + jj] = v[u];
    }
  }
  for (int c = TID; c < 128; c += 320) {
    int i = c & 15, kb = 10 + ((c >> 4) & 1), g = c >> 5;
    *(short8*)(Vt + ((g * 12 + kb) * 16 + i) * 8) = short8{};
  }
  __syncthreads();
  int w = TID >> 6, lane = TID & 63;
  int li = lane & 15, lg = lane >> 4;
  short8 aq[2];
#pragma unroll
  for (int ks = 0; ks < 2; ++ks)
    aq[ks] = *(const short8*)(qkv + (size_t)(base + w * 16 + li) * 1536 + h * 64 + ks * 32 + lg * 8);
  f32x4 accs[5] = {};
#pragma unroll
  for (int t = 0; t < 5; ++t)
#pragma unroll
    for (int ks = 0; ks < 2; ++ks) {
      short8 bk = *(const short8*)(Kf + ((t * 8 + ks * 4 + lg) * 16 + li) * 8);
      accs[t] = __builtin_amdgcn_mfma_f32_16x16x32_bf16(aq[ks], bk, accs[t], 0, 0, 0);
    }
  int rowg = w * 16 + lg * 4;
#pragma unroll
  for (int r = 0; r < 4; ++r) {
    int row = rowg + r;
    float v[5];
    float mx = -1e30f;
#pragma unroll
    for (int t = 0; t < 5; ++t) {
      int col = t * 16 + li;
      float x = accs[t][r] * 0.125f;
      bool ok = (col < S) && (col <= row);
      v[t] = ok ? x : -1e30f;
      mx = fmaxf(mx, v[t]);
    }
#pragma unroll
    for (int off = 1; off < 16; off <<= 1) mx = fmaxf(mx, __shfl_xor(mx, off, 64));
    float sum = 0.f;
#pragma unroll
    for (int t = 0; t < 5; ++t) {
      v[t] = (v[t] > -1e29f) ? __expf(v[t] - mx) : 0.f;
      sum += v[t];
    }
#pragma unroll
    for (int off = 1; off < 16; off <<= 1) sum += __shfl_xor(sum, off, 64);
    float inv = __fdividef(1.f, sum);
#pragma unroll
    for (int t = 0; t < 5; ++t) {
      int c = t * 16 + li;
      Pf[w][((c >> 3) * 16 + (row - w * 16)) * 8 + (c & 7)] = f2bf(v[t] * inv);
    }
  }
  for (int z = lane; z < 256; z += 64) {
    int kb = 10 + (z >> 7);
    int rem = z & 127;
    Pf[w][(kb * 16 + (rem >> 3)) * 8 + (rem & 7)] = 0;
  }
  f32x4 acco[4] = {};
#pragma unroll
  for (int s = 0; s < 3; ++s) {
    short8 ap = *(const short8*)(Pf[w] + ((s * 4 + lg) * 16 + li) * 8);
#pragma unroll
    for (int n = 0; n < 4; ++n) {
      short8 bv = *(const short8*)(Vt + ((n * 12 + s * 4 + lg) * 16 + li) * 8);
      acco[n] = __builtin_amdgcn_mfma_f32_16x16x32_bf16(ap, bv, acco[n], 0, 0, 0);
    }
  }
#pragma unroll
  for (int n = 0; n < 4; ++n)
#pragma unroll
    for (int r = 0; r < 4; ++r) {
      int row = rowg + r;
      if (row < S) O[(size_t)(base + row) * 512 + h * 64 + n * 16 + li] = f2bf(acco[n][r]);
    }
}

// ---------------- agg attention (fp32 math, S=9): QKV f32 in, bf16 out ----------------
__global__ __launch_bounds__(256) void attn_k(const float* __restrict__ qkv,
                                              short* __restrict__ O, int S, int causal) {
  int blk = blockIdx.x;
  int p = blk >> 3, h = blk & 7;
  __shared__ float Qs[Ltok][68], Ks[Ltok][68], Vs[Ltok][68];
  __shared__ float ps[4][132];
  int base = p * S;
  for (int idx = TID; idx < S * 16; idx += 256) {
    int j = idx >> 4, c = idx & 15;
    const float4* q = (const float4*)(qkv + (size_t)(base + j) * 1536 + h * 64);
    const float4* k = (const float4*)(qkv + (size_t)(base + j) * 1536 + 512 + h * 64);
    const float4* v = (const float4*)(qkv + (size_t)(base + j) * 1536 + 1024 + h * 64);
    ((float4*)&Qs[j][0])[c] = q[c];
    ((float4*)&Ks[j][0])[c] = k[c];
    ((float4*)&Vs[j][0])[c] = v[c];
  }
  __syncthreads();
  int wave = TID >> 6, lane = TID & 63;
  bool val0 = lane < S, val1 = lane + 64 < S;
  int j0 = val0 ? lane : 0;
  int j1 = val1 ? lane + 64 : 0;
  const float4* k0p = (const float4*)&Ks[j0][0];
  const float4* k1p = (const float4*)&Ks[j1][0];
  for (int i = wave; i < S; i += 4) {
    const float4* q4 = (const float4*)&Qs[i][0];
    float a0 = 0.f, a1 = 0.f;
#pragma unroll
    for (int d4 = 0; d4 < 16; ++d4) {
      float4 qv = q4[d4], k0v = k0p[d4], k1v = k1p[d4];
      a0 += qv.x * k0v.x + qv.y * k0v.y + qv.z * k0v.z + qv.w * k0v.w;
      a1 += qv.x * k1v.x + qv.y * k1v.y + qv.z * k1v.z + qv.w * k1v.w;
    }
    float m0 = (val0 && (!causal || lane <= i)) ? a0 * 0.125f : -1e30f;
    float m1 = (val1 && (!causal || lane + 64 <= i)) ? a1 * 0.125f : -1e30f;
    float mx = fmaxf(m0, m1);
#pragma unroll
    for (int off = 32; off; off >>= 1) mx = fmaxf(mx, __shfl_xor(mx, off, 64));
    float e0 = expf(m0 - mx), e1 = expf(m1 - mx);
    float sum = e0 + e1;
#pragma unroll
    for (int off = 32; off; off >>= 1) sum += __shfl_xor(sum, off, 64);
    float inv = 1.f / sum;
    ps[wave][lane] = e0 * inv;
    ps[wave][lane + 64] = e1 * inv;
    float o = 0.f;
    for (int j = 0; j < S; ++j) o += ps[wave][j] * Vs[j][lane];
    O[(base + i) * Dm + h * 64 + lane] = f2bf(o);
  }
}

// ---------------- final LN + eos gather + text_proj + L2 normalize (fp32) ----------------
__global__ __launch_bounds__(256) void feats_k(const float* __restrict__ X,
                                               const int* __restrict__ eosl,
                                               const float* __restrict__ g,
                                               const float* __restrict__ bb,
                                               const float* __restrict__ proj,
                                               float* __restrict__ feats, int p0) {
  int pl = blockIdx.x;
  int p = p0 + pl;
  int e = eosl[p];
  const float* x = X + (size_t)(pl * Ltok + e) * Dm;
  __shared__ float row[Dm];
  __shared__ float s1[256], s2[256];
  float v0 = x[TID], v1 = x[TID + 256];
  s1[TID] = v0 + v1;
  s2[TID] = v0 * v0 + v1 * v1;
  __syncthreads();
  for (int s = 128; s; s >>= 1) {
    if (TID < s) { s1[TID] += s1[TID + s]; s2[TID] += s2[TID + s]; }
    __syncthreads();
  }
  float mean = s1[0] * (1.f / 512.f);
  float var = s2[0] * (1.f / 512.f) - mean * mean;
  float inv = rsqrtf(var + 1e-5f);
  row[TID] = (v0 - mean) * inv * g[TID] + bb[TID];
  row[TID + 256] = (v1 - mean) * inv * g[TID + 256] + bb[TID + 256];
  __syncthreads();
  float a0 = 0.f, a1 = 0.f;
  for (int d = 0; d < Dm; ++d) {
    float r = row[d];
    a0 += r * proj[d * Dm + TID];
    a1 += r * proj[d * Dm + TID + 256];
  }
  s1[TID] = a0 * a0 + a1 * a1;
  __syncthreads();
  for (int s = 128; s; s >>= 1) { if (TID < s) s1[TID] += s1[TID + s]; __syncthreads(); }
  float sc = 1.f / sqrtf(s1[0]);
  feats[p * Dm + TID] = a0 * sc;
  feats[p * Dm + TID + 256] = a1 * sc;
}

// ---------------- rerank + fuse + scatter ----------------
__global__ void rerank_k(const float* __restrict__ sampled, const float* __restrict__ feats,
                         const int* __restrict__ selidx, const int* __restrict__ topk,
                         const float* __restrict__ logits, float* __restrict__ out1,
                         float* __restrict__ out3) {
  int idx = blockIdx.x;
  int s = idx / KTOP;
  int lane = TID;
  float acc = 0.f;
  for (int d = lane; d < Dm; d += 64) acc += sampled[s * Dm + d] * feats[idx * Dm + d];
#pragma unroll
  for (int off = 32; off; off >>= 1) acc += __shfl_down(acc, off, 64);
  if (lane == 0) {
    out1[idx] = acc;
    int row = selidx[s];
    int cls = topk[idx];
    float sl = logits[row * C1 + cls];
    float a = sigf(sl), b = sigf(acc);
    float fused = powf(a, 0.75f) * powf(b, 0.25f);
    float xx = fminf(fmaxf(fused, 0.f), 1.f);
    float x1 = fmaxf(xx, 1e-5f);
    float x2 = fmaxf(1.f - xx, 1e-5f);
    out3[row * C1 + cls] = logf(x1 / x2);
  }
}

// ============================ host ============================
static inline size_t alup(size_t x) { return (x + 255) & ~(size_t)255; }

constexpr size_t WT_QKV = (size_t)NL * Dm * 3 * Dm;
constexpr size_t WT_OUT = (size_t)NL * Dm * Dm;
constexpr size_t WT_FC  = (size_t)NL * Dm * MLPD;
constexpr size_t WT_PR  = (size_t)NL * MLPD * Dm;
constexpr size_t WT_ALL = WT_QKV + WT_OUT + WT_FC + WT_PR;
constexpr size_t MAGG   = (size_t)Pn * 9;  // 1440

static void plan_rows(int PC, size_t* rows_o, size_t* RP_o) {
  size_t rows = (size_t)PC * Ltok;
  if (rows < MAGG) rows = MAGG;
  size_t RP = (rows + 255) & ~(size_t)255;
  *rows_o = rows; *RP_o = RP;
}

static size_t plan_bytes(int PC) {
  size_t rows, RP;
  plan_rows(PC, &rows, &RP);
  size_t tot = 0;
  tot += alup(Bsz * Dm * 4);                  // h
  tot += alup(Bsz * 8);                       // entropy
  tot += alup(KSEL * 4);                      // selidx
  tot += alup(Pn * 4);                        // topk
  tot += alup(Pn * 4);                        // eosl
  tot += alup(KSEL * Dm * 4);                 // hsel
  tot += alup(KSEL * Dm * 4);                 // sampled
  tot += alup(Pn * NINS * Dm * 4);            // insbuf
  tot += alup(Pn * Dm * 4);                   // feats
  tot += alup(rows * Dm * 4);                 // X f32
  tot += alup(RP * Dm * 2);                   // Abuf bf16
  tot += alup(RP * Dm * 2);                   // Obuf bf16
  tot += alup(MAGG * 3 * Dm * 4);             // QKV f32 (agg only)
  tot += alup(RP * 3 * Dm * 2);               // QKVb bf16 (txt)
  tot += alup(RP * MLPD * 2);                 // Hb bf16
  tot += 2 * alup(WT_ALL * 2);                // bf16 weights (agg + txt)
  tot += alup((size_t)8 * Bsz * Dm * 4);      // P_lin
  tot += alup((size_t)4 * Bsz * C1 * 4);      // P_zs
  tot += alup((size_t)8 * KSEL * Dm * 4);     // P_smp
  tot += alup((size_t)16 * MAGG * Dm * 4);    // P_sk (agg split-K, S<=16)
  return tot;
}

extern "C" void kernel_launch(void* const* d_in, const int* in_sizes, int n_in,
                              void* d_out, int out_size, void* d_ws, size_t ws_size,
                              hipStream_t stream) {
  const float* x         = (const float*)d_in[0];
  const float* linear_w  = (const float*)d_in[1];
  const float* linear_b  = (const float*)d_in[2];
  const float* zs_w      = (const float*)d_in[3];
  const float* sample_w  = (const float*)d_in[4];
  const float* sample_b  = (const float*)d_in[5];
  const float* ins_token = (const float*)d_in[6];
  const float* token_seq = (const float*)d_in[7];
  const float* exemplar  = (const float*)d_in[8];
  const int*   eos_index = (const int*)d_in[9];
  const float* agg_ln1_g = (const float*)d_in[10];
  const float* agg_ln1_b = (const float*)d_in[11];
  const float* agg_qkv_w = (const float*)d_in[12];
  const float* agg_qkv_b = (const float*)d_in[13];
  const float* agg_out_w = (const float*)d_in[14];
  const float* agg_out_b = (const float*)d_in[15];
  const float* agg_ln2_g = (const float*)d_in[16];
  const float* agg_ln2_b = (const float*)d_in[17];
  const float* agg_fc_w  = (const float*)d_in[18];
  const float* agg_fc_b  = (const float*)d_in[19];
  const float* agg_pr_w  = (const float*)d_in[20];
  const float* agg_pr_b  = (const float*)d_in[21];
  const float* pos_emb   = (const float*)d_in[22];
  const float* txt_ln1_g = (const float*)d_in[23];
  const float* txt_ln1_b = (const float*)d_in[24];
  const float* txt_qkv_w = (const float*)d_in[25];
  const float* txt_qkv_b = (const float*)d_in[26];
  const float* txt_out_w = (const float*)d_in[27];
  const float* txt_out_b = (const float*)d_in[28];
  const float* txt_ln2_g = (const float*)d_in[29];
  const float* txt_ln2_b = (const float*)d_in[30];
  const float* txt_fc_w  = (const float*)d_in[31];
  const float* txt_fc_b  = (const float*)d_in[32];
  const float* txt_pr_w  = (const float*)d_in[33];
  const float* txt_pr_b  = (const float*)d_in[34];
  const float* lnf_g     = (const float*)d_in[35];
  const float* lnf_b     = (const float*)d_in[36];
  const float* text_proj = (const float*)d_in[37];

  float* out0 = (float*)d_out;
  float* out1 = out0 + Bsz * C1;
  float* out2 = out1 + KSEL * KTOP;
  float* out3 = out2 + KSEL;

  int PC = 20;
  const int cands[4] = {160, 80, 40, 20};
  for (int i = 0; i < 4; ++i)
    if (plan_bytes(cands[i]) <= ws_size) { PC = cands[i]; break; }
  int NC = Pn / PC;

  char* wp = (char*)d_ws;
  auto carve = [&](size_t bytes) -> void* { void* r = (void*)wp; wp += alup(bytes); return r; };
  size_t rows, RP;
  plan_rows(PC, &rows, &RP);

  float* h       = (float*)carve(Bsz * Dm * 4);
  double* ent    = (double*)carve(Bsz * 8);
  int* selidx    = (int*)carve(KSEL * 4);
  int* topk      = (int*)carve(Pn * 4);
  int* eosl      = (int*)carve(Pn * 4);
  float* hsel    = (float*)carve(KSEL * Dm * 4);
  float* sampled = (float*)carve(KSEL * Dm * 4);
  float* insbuf  = (float*)carve(Pn * NINS * Dm * 4);
  float* feats   = (float*)carve(Pn * Dm * 4);
  float* X       = (float*)carve(rows * Dm * 4);
  short* Abuf    = (short*)carve(RP * Dm * 2);
  short* Obuf    = (short*)carve(RP * Dm * 2);
  float* QKV     = (float*)carve(MAGG * 3 * Dm * 4);
  short* QKVb    = (short*)carve(RP * 3 * Dm * 2);
  short* Hb      = (short*)carve(RP * MLPD * 2);
  short* wtA     = (short*)carve(WT_ALL * 2);
  short* wtT     = (short*)carve(WT_ALL * 2);
  float* Plin    = (float*)carve((size_t)8 * Bsz * Dm * 4);
  float* Pzs     = (float*)carve((size_t)4 * Bsz * C1 * 4);
  float* Psmp    = (float*)carve((size_t)8 * KSEL * Dm * 4);
  float* Psk     = (float*)carve((size_t)16 * MAGG * Dm * 4);

  short* wtA_qkv = wtA;
  short* wtA_out = wtA_qkv + WT_QKV;
  short* wtA_fc  = wtA_out + WT_OUT;
  short* wtA_pr  = wtA_fc + WT_FC;
  short* wtT_qkv = wtT;
  short* wtT_out = wtT_qkv + WT_QKV;
  short* wtT_fc  = wtT_out + WT_OUT;
  short* wtT_pr  = wtT_fc + WT_FC;

  dim3 blk(256);
  auto wconv = [&](const float* W, short* Wt, int K, int N) {
    dim3 g(N / 32, K / 32, NL);
    wconv_k<<<g, blk, 0, stream>>>(W, Wt, K, N);
  };
  auto bgemm = [&](const short* A, const short* Wt, const float* bias, float* Cf, short* Cb,
                   float* Xres, int M, int N, int K, int mode) {
    if (M >= 2048 && N >= 1536) {
      dim3 g(N / 128, (M + 255) / 256);
      bgemm_tall_k<<<g, dim3(512), 0, stream>>>(A, Wt, bias, Cf, Cb, Xres, M, N, K, mode);
    } else {
      dim3 g(N / 128, (M + 127) / 128);
      bgemm_k<<<g, blk, 0, stream>>>(A, Wt, bias, Cf, Cb, Xres, M, N, K, mode);
    }
  };
  // split-K residual GEMM (agg starved cases): partials + deterministic reduce
  auto bgemm_res_sk = [&](const short* A, const short* Wt, const float* bias, float* Xres,
                          int M, int N, int K, int S) {
    dim3 g(N / 128, (M + 127) / 128, S);
    bgemm_sk_k<<<g, blk, 0, stream>>>(A, Wt, Psk, M, N, K, K / S);
    int MN = M * N;
    reduce_res_k<<<(MN + 255) / 256, blk, 0, stream>>>(Psk, bias, Xres, MN, N, S);
  };
  auto gemm32s = [&](const float* A, const float* W, float* P, int M, int N, int K, int S) {
    dim3 g((N + 63) / 64, (M + 63) / 64, S);
    gemm32s_k<<<g, blk, 0, stream>>>(A, W, P, M, N, K, K / S);
  };
  auto reduce = [&](const float* P, const float* bias, float* C, float* C2, int MN, int N, int S) {
    reduce_k<<<(MN + 255) / 256, blk, 0, stream>>>(P, bias, C, C2, MN, N, S);
  };
  auto ln = [&](const float* Xp, const float* g, const float* b, short* A, int M) {
    ln_k<<<M / 2, blk, 0, stream>>>(Xp, g, b, A);
  };

  // ---- weight preconvert+transpose (bf16 [N,K]) ----
  wconv(agg_qkv_w, wtA_qkv, Dm, 3 * Dm);
  wconv(agg_out_w, wtA_out, Dm, Dm);
  wconv(agg_fc_w,  wtA_fc,  Dm, MLPD);
  wconv(agg_pr_w,  wtA_pr,  MLPD, Dm);
  wconv(txt_qkv_w, wtT_qkv, Dm, 3 * Dm);
  wconv(txt_out_w, wtT_out, Dm, Dm);
  wconv(txt_fc_w,  wtT_fc,  Dm, MLPD);
  wconv(txt_pr_w,  wtT_pr,  MLPD, Dm);

  // ---- base classifier (fp32 split-K, exact/deterministic) ----
  gemm32s(x, linear_w, Plin, Bsz, Dm, DIN, 8);
  reduce(Plin, linear_b, h, nullptr, Bsz * Dm, Dm, 8);
  rownorm_k<<<Bsz, blk, 0, stream>>>(h);
  gemm32s(h, zs_w, Pzs, Bsz, C1, Dm, 4);
  reduce(Pzs, nullptr, out0, out3, Bsz * C1, C1, 4);
  entropy_k<<<Bsz, blk, 0, stream>>>(out0, ent);
  top32_k<<<1, blk, 0, stream>>>(ent, selidx, out2);
  top5_k<<<KSEL, blk, 0, stream>>>(out0, selidx, topk);
  eos_k<<<1, blk, 0, stream>>>(eos_index, topk, eosl);
  gather_h_k<<<KSEL, blk, 0, stream>>>(h, selidx, hsel);
  gemm32s(hsel, sample_w, Psmp, KSEL, Dm, Dm, 8);
  reduce(Psmp, sample_b, sampled, nullptr, KSEL * Dm, Dm, 8);

  // ---- aggregator transformer (S=9, 160 seqs, no mask; fp32 attention) ----
  build_agg_k<<<Pn * 9, blk, 0, stream>>>(ins_token, sampled, exemplar, topk, X);
  {
    int M = (int)MAGG;  // 1440
    for (int i = 0; i < NL; ++i) {
      ln(X, agg_ln1_g + i * Dm, agg_ln1_b + i * Dm, Abuf, M);
      bgemm(Abuf, wtA_qkv + (size_t)i * Dm * 3 * Dm, agg_qkv_b + i * 3 * Dm, QKV, nullptr, nullptr, M, 3 * Dm, Dm, 0);
      attn_k<<<Pn * NHEAD, blk, 0, stream>>>(QKV, Obuf, 9, 0);
      bgemm_res_sk(Obuf, wtA_out + (size_t)i * Dm * Dm, agg_out_b + i * Dm, X, M, Dm, Dm, 8);
      ln(X, agg_ln2_g + i * Dm, agg_ln2_b + i * Dm, Abuf, M);
      bgemm(Abuf, wtA_fc + (size_t)i * Dm * MLPD, agg_fc_b + i * MLPD, nullptr, Hb, nullptr, M, MLPD, Dm, 2);
      bgemm_res_sk(Hb, wtA_pr + (size_t)i * MLPD * Dm, agg_pr_b + i * Dm, X, M, Dm, MLPD, 16);
    }
  }
  save_ins_k<<<Pn, blk, 0, stream>>>(X, insbuf);

  // ---- text transformer (S=77, causal; MFMA attention), chunked over sequences ----
  for (int c = 0; c < NC; ++c) {
    int p0 = c * PC;
    int M = PC * Ltok;
    build_txt_k<<<PC * Ltok, blk, 0, stream>>>(token_seq, insbuf, pos_emb, topk, X, p0);
    for (int i = 0; i < NL; ++i) {
      ln(X, txt_ln1_g + i * Dm, txt_ln1_b + i * Dm, Abuf, M);
      bgemm(Abuf, wtT_qkv + (size_t)i * Dm * 3 * Dm, txt_qkv_b + i * 3 * Dm, nullptr, QKVb, nullptr, M, 3 * Dm, Dm, 3);
      attn_tx_k<<<dim3(PC * NHEAD), dim3(320), 0, stream>>>(QKVb, Obuf, Ltok);
      bgemm(Obuf, wtT_out + (size_t)i * Dm * Dm, txt_out_b + i * Dm, nullptr, nullptr, X, M, Dm, Dm, 1);
      ln(X, txt_ln2_g + i * Dm, txt_ln2_b + i * Dm, Abuf, M);
      bgemm(Abuf, wtT_fc + (size_t)i * Dm * MLPD, txt_fc_b + i * MLPD, nullptr, Hb, nullptr, M, MLPD, Dm, 2);
      bgemm(Hb, wtT_pr + (size_t)i * MLPD * Dm, txt_pr_b + i * Dm, nullptr, nullptr, X, M, Dm, MLPD, 1);
    }
    feats_k<<<PC, blk, 0, stream>>>(X, eosl, lnf_g, lnf_b, text_proj, feats, p0);
  }

  // ---- rerank + fuse + scatter ----
  rerank_k<<<Pn, dim3(64), 0, stream>>>(sampled, feats, selidx, topk, out0, out1, out3);
}